// Round 16
// baseline (201.588 us; speedup 1.0000x reference)
//
#include <hip/hip_runtime.h>

typedef unsigned short ushort_t;
typedef unsigned int uint_t;
typedef unsigned long long u64;
typedef __attribute__((ext_vector_type(8))) short bf16x8;
typedef __attribute__((ext_vector_type(4))) float f32x4;
typedef __attribute__((ext_vector_type(16))) float f32x16;
typedef __attribute__((ext_vector_type(4))) uint_t u32x4;

#define B_ 8
#define L_ 1024
#define C_ 768
#define H_ 6
#define D_ 128
#define BH_ 48
#define NEGINF (-1e9f)
#define THR_ 8.0f

#define AS1 __attribute__((address_space(1)))
#define AS3 __attribute__((address_space(3)))

// round-to-nearest-even f32 -> bf16
__device__ __forceinline__ ushort_t f2bf(float f) {
  uint_t u = __builtin_bit_cast(uint_t, f);
  u += 0x7fffu + ((u >> 16) & 1u);
  return (ushort_t)(u >> 16);
}
__device__ __forceinline__ float bf2f(ushort_t s) {
  uint_t u = ((uint_t)s) << 16;
  return __builtin_bit_cast(float, u);
}

// ---------------------------------------------------------------- converts
__global__ void cvt_f32_bf16(const float* __restrict__ in, ushort_t* __restrict__ out, int n8) {
  int i = blockIdx.x * 256 + threadIdx.x;
  if (i >= n8) return;
  const float4* p = (const float4*)in + (size_t)i * 2;
  float4 a = p[0], b = p[1];
  uint4 r;
  r.x = (uint_t)f2bf(a.x) | ((uint_t)f2bf(a.y) << 16);
  r.y = (uint_t)f2bf(a.z) | ((uint_t)f2bf(a.w) << 16);
  r.z = (uint_t)f2bf(b.x) | ((uint_t)f2bf(b.y) << 16);
  r.w = (uint_t)f2bf(b.z) | ((uint_t)f2bf(b.w) << 16);
  ((uint4*)out)[i] = r;
}

// ------------------------------------------------- bit-pack a1 / d<=2 / d<=3
__global__ __launch_bounds__(256)
void pack_masks(const int* __restrict__ adj, const int* __restrict__ dist,
                u64* __restrict__ a1p, u64* __restrict__ d2p, u64* __restrict__ d3p) {
  int l = blockIdx.x, b = blockIdx.y, t = threadIdx.x;
  size_t base = ((size_t)b * L_ + l) * L_;
  size_t rb = ((size_t)b * L_ + l) * 16;
  #pragma unroll
  for (int it = 0; it < 4; ++it) {
    int c = it * 256 + t;
    int av = adj[base + c];
    int dv = dist[base + c];
    u64 m1 = __ballot((av > 0) || (c == l));
    u64 m2 = __ballot(dv <= 2);
    u64 m3 = __ballot(dv <= 3);
    if ((t & 63) == 0) {
      int w = it * 4 + (t >> 6);
      a1p[rb + w] = m1; d2p[rb + w] = m2; d3p[rb + w] = m3;
    }
  }
}

// ------------------------------------------------- 2-hop closure (bit OR)
__global__ __launch_bounds__(64)
void hop2(const u64* __restrict__ a1p, u64* __restrict__ a2p) {
  int tid = blockIdx.x * 64 + threadIdx.x;   // 0..8191 = (b,l)
  int b = tid >> 10;
  size_t rb = (size_t)tid * 16;
  u64 row[16], acc[16];
  #pragma unroll
  for (int j = 0; j < 16; ++j) { row[j] = a1p[rb + j]; acc[j] = 0ULL; }
  bool done = false;
  #pragma unroll
  for (int mw = 0; mw < 16; ++mw) {
    if (done) continue;
    u64 bits = row[mw];
    while (bits) {
      int tz = __builtin_ctzll(bits); bits &= bits - 1;
      const u64* src = a1p + (((size_t)b << 10) + (mw << 6) + tz) * 16;
      u64 band = ~0ULL;
      #pragma unroll
      for (int j = 0; j < 16; ++j) { acc[j] |= src[j]; band &= acc[j]; }
      if (band == ~0ULL) { done = true; break; }
    }
  }
  #pragma unroll
  for (int j = 0; j < 16; ++j) a2p[rb + j] = acc[j];
}

// ------------------------------------------------- bf16 GEMM  C = A @ B^T
// 128x128 tile, BK=64, T2 both-sides XOR swizzle, bijective XCD swizzle.
// EPI==0 epilogue is BLOCK-UNIFORM in sec (n-tiles 128-wide, 768%128==0).
template<int EPI>
__global__ __launch_bounds__(256)
void gemm_bt(const ushort_t* __restrict__ A, const ushort_t* __restrict__ Bm,
             int N, int K,
             ushort_t* __restrict__ qo, ushort_t* __restrict__ ko,
             ushort_t* __restrict__ vTo, ushort_t* __restrict__ vo,
             float* __restrict__ fo) {
  __shared__ __align__(16) ushort_t As[128 * 64];   // 16 KB
  __shared__ __align__(16) ushort_t Bs[128 * 64];   // 16 KB
  int t = threadIdx.x;
  int lane = t & 63, lo = lane & 15, hi = lane >> 4;
  int wv = t >> 6, wm = wv >> 1, wn = wv & 1;

  int gx = gridDim.x;
  int nwg = gx * gridDim.y;
  int orig = blockIdx.y * gx + blockIdx.x;
  int cpx = nwg >> 3;
  int wg = (orig & 7) * cpx + (orig >> 3);
  int n0 = (wg % gx) * 128;
  int m0 = (wg / gx) * 128;

  f32x4 acc[4][4];
  #pragma unroll
  for (int mi = 0; mi < 4; ++mi)
    #pragma unroll
    for (int ni = 0; ni < 4; ++ni) acc[mi][ni] = (f32x4){0.f, 0.f, 0.f, 0.f};

  for (int kt = 0; kt < K; kt += 64) {
    #pragma unroll
    for (int i = 0; i < 4; ++i) {
      int u = i * 256 + t;                 // 0..1023
      int row = u >> 3, c16 = u & 7;
      int sc = c16 ^ (row & 7);
      __builtin_amdgcn_global_load_lds(
          (const AS1 void*)(A + ((size_t)(m0 + row) * K + kt + sc * 8)),
          (AS3 void*)&As[(size_t)u * 8], 16, 0, 0);
      __builtin_amdgcn_global_load_lds(
          (const AS1 void*)(Bm + ((size_t)(n0 + row) * K + kt + sc * 8)),
          (AS3 void*)&Bs[(size_t)u * 8], 16, 0, 0);
    }
    __syncthreads();
    #pragma unroll
    for (int kks = 0; kks < 2; ++kks) {
      bf16x8 af[4], bfr[4];
      #pragma unroll
      for (int mi = 0; mi < 4; ++mi) {
        int r = wm * 64 + mi * 16 + lo;
        af[mi] = *(const bf16x8*)&As[r * 64 + (((kks * 4 + hi) ^ (r & 7)) * 8)];
      }
      #pragma unroll
      for (int ni = 0; ni < 4; ++ni) {
        int r = wn * 64 + ni * 16 + lo;
        bfr[ni] = *(const bf16x8*)&Bs[r * 64 + (((kks * 4 + hi) ^ (r & 7)) * 8)];
      }
      #pragma unroll
      for (int mi = 0; mi < 4; ++mi)
        #pragma unroll
        for (int ni = 0; ni < 4; ++ni)
          acc[mi][ni] = __builtin_amdgcn_mfma_f32_16x16x32_bf16(af[mi], bfr[ni], acc[mi][ni], 0, 0, 0);
    }
    __syncthreads();
  }

  // epilogue. D layout: col = lane&15, row = (lane>>4)*4 + j  [m89-verified]
  if (EPI == 1) {
    #pragma unroll
    for (int mi = 0; mi < 4; ++mi) {
      int rbase = m0 + wm * 64 + mi * 16 + hi * 4;
      #pragma unroll
      for (int ni = 0; ni < 4; ++ni) {
        int c = n0 + wn * 64 + ni * 16 + lo;
        f32x4 v = acc[mi][ni];
        #pragma unroll
        for (int j = 0; j < 4; ++j)
          fo[(size_t)(rbase + j) * N + c] = v[j];
      }
    }
    return;
  }
  // EPI == 0: block-uniform section
  int sec = n0 / 768;
  if (sec < 2) {
    #pragma unroll
    for (int mi = 0; mi < 4; ++mi) {
      int rbase = m0 + wm * 64 + mi * 16 + hi * 4;
      #pragma unroll
      for (int ni = 0; ni < 4; ++ni) {
        int cc = n0 - sec * 768 + wn * 64 + ni * 16 + lo;
        int hh = cc >> 7, dd = cc & 127;
        f32x4 v = acc[mi][ni];
        #pragma unroll
        for (int j = 0; j < 4; ++j) {
          int r = rbase + j;
          int b = r >> 10, l = r & 1023;
          size_t bh = (size_t)(b * H_ + hh);
          if (sec == 0) qo[(bh * L_ + l) * D_ + dd] = f2bf(v[j] * 0.08838834764831845f);
          else          ko[(bh * L_ + l) * D_ + dd] = f2bf(v[j]);
        }
      }
    }
    return;
  }
  // sec == 2: V third. h is block-uniform.
  int hh = (n0 - 1536) >> 7;
  int b = m0 >> 10, l0 = m0 & 1023;
  size_t bh = (size_t)(b * H_ + hh);
  if (hh == 0) {
    // eye head: only row-major v needed
    #pragma unroll
    for (int mi = 0; mi < 4; ++mi) {
      int lb = wm * 64 + mi * 16 + hi * 4;
      #pragma unroll
      for (int ni = 0; ni < 4; ++ni) {
        int dd = wn * 64 + ni * 16 + lo;
        f32x4 v = acc[mi][ni];
        #pragma unroll
        for (int j = 0; j < 4; ++j)
          vo[(bh * L_ + l0 + lb + j) * D_ + dd] = f2bf(v[j]);
      }
    }
    return;
  }
  // h != 0: only vT needed. LDS transpose, XOR (dd&7)<<4 both sides.
  #pragma unroll
  for (int mi = 0; mi < 4; ++mi) {
    int lb = wm * 64 + mi * 16 + hi * 4;
    #pragma unroll
    for (int ni = 0; ni < 4; ++ni) {
      int dd = wn * 64 + ni * 16 + lo;
      ushort_t* base = (dd < 64) ? As : Bs;
      f32x4 v = acc[mi][ni];
      #pragma unroll
      for (int j = 0; j < 4; ++j) {
        int byte = (((dd & 63) * 256 + (lb + j) * 2)) ^ ((dd & 7) << 4);
        *(ushort_t*)((char*)base + byte) = f2bf(v[j]);
      }
    }
  }
  __syncthreads();
  #pragma unroll
  for (int i = 0; i < 8; ++i) {
    int u = i * 256 + t;            // 2048 chunks: dd 0..127 x 16 16B-chunks
    int ddl = u >> 4, c16 = u & 15;
    const ushort_t* base = (ddl < 64) ? As : Bs;
    int byte = (((ddl & 63) * 256 + c16 * 16)) ^ ((ddl & 7) << 4);
    bf16x8 val = *(const bf16x8*)((const char*)base + byte);
    *(bf16x8*)(vTo + (bh * D_ + ddl) * L_ + l0 + c16 * 8) = val;
  }
}

// ------------------------------------------------- flash attention, split-K=4
// 8 waves / block, TWO q-tiles per wave (512 q-rows/block): each staged K/V
// chunk is amortized over 2x the q-rows. Tile-0 Q in registers; tile-1 Q in
// LDS (staged once, pre-swizzled source, same ^(row&15) slot swizzle as Ks).
// kv quarter per blockIdx.z; KVBLK=32, 8 chunks/block.
__global__ __launch_bounds__(512)
void attn_kernel(const ushort_t* __restrict__ q, const ushort_t* __restrict__ k,
                 const ushort_t* __restrict__ vT, const ushort_t* __restrict__ v,
                 ushort_t* __restrict__ obf,
                 ushort_t* __restrict__ np0, ushort_t* __restrict__ np1,
                 ushort_t* __restrict__ np2, ushort_t* __restrict__ np3,
                 float* __restrict__ ml,
                 const u64* __restrict__ a1p, const u64* __restrict__ a2p,
                 const u64* __restrict__ d2p, const u64* __restrict__ d3p) {
  __shared__ __align__(16) ushort_t Ks[2][32 * 128];   // 8 KB x2
  __shared__ __align__(16) ushort_t Vs[2][128 * 32];   // 8 KB x2
  __shared__ __align__(16) ushort_t Qs[8][32 * 128];   // tile-1 Q per wave, 64 KB
  int t = threadIdx.x;
  int lane = t & 63, lo32 = lane & 31, hi2 = (lane >> 5) & 1, wv = t >> 6;
  int bh = blockIdx.x, qt = blockIdx.y, quar = blockIdx.z;
  int b = bh / H_, h = bh - b * H_;
  int qbase = qt * 512;
  int qw = qbase + wv * 32;          // tile 0; tile 1 = qw + 256
  int kvb = quar * 256;

  if (h == 0) {
    if (quar) return;
    // eye mask: out = v[l]  (h*D_ == 0 in output); 512 rows
    const ushort_t* vp0 = v + ((size_t)bh * L_ + qbase) * D_;
    ushort_t* op0 = obf + ((size_t)b * L_ + qbase) * C_;
    #pragma unroll
    for (int it = 0; it < 16; ++it) {
      int u = it * 512 + t;
      int r = u >> 4, c = (u & 15) * 8;
      *(bf16x8*)(op0 + (size_t)r * C_ + c) = *(const bf16x8*)(vp0 + (size_t)r * D_ + c);
    }
    return;
  }

  const ushort_t* qp = q + (size_t)bh * L_ * D_;
  const ushort_t* kp = k + (size_t)bh * L_ * D_ + (size_t)kvb * D_;
  const ushort_t* vp = vT + (size_t)bh * D_ * L_ + kvb;

  // prologue: stage tile-1 Q into Qs (wave-local 8 KB; uniform-base+lane*16
  // dest, pre-swizzled source col16 ^= row&15)
  #pragma unroll
  for (int i = 0; i < 8; ++i) {
    int u = i * 64 + lane;               // 0..511 within wave
    int row = u >> 4, c16 = u & 15;
    int sc = c16 ^ (row & 15);
    __builtin_amdgcn_global_load_lds(
        (const AS1 void*)(qp + (size_t)(qw + 256 + row) * D_ + sc * 8),
        (AS3 void*)&Qs[wv][(size_t)u * 8], 16, 0, 0);
  }
  // tile-0 Q fragments in registers
  bf16x8 qf0[8];
  #pragma unroll
  for (int dt = 0; dt < 8; ++dt)
    qf0[dt] = *(const bf16x8*)(qp + (size_t)(qw + lo32) * D_ + dt * 16 + hi2 * 8);

  const u64* mp = (h == 1) ? a1p : (h == 2) ? a2p : (h == 3) ? d2p : d3p;
  bool full = (h == 5);
  const u64* mrow0 = mp + ((size_t)b * L_ + qw + lo32) * 16 + quar * 4;
  const u64* mrow1 = mrow0 + (size_t)256 * 16;

  float m_run[2] = {NEGINF, NEGINF}, l_run[2] = {0.f, 0.f};
  f32x16 acc[2][4];
  #pragma unroll
  for (int tl = 0; tl < 2; ++tl)
    #pragma unroll
    for (int dt = 0; dt < 4; ++dt)
      #pragma unroll
      for (int r = 0; r < 16; ++r) acc[tl][dt][r] = 0.f;

  auto stage = [&](int buf, int ch) {
    int kc0 = ch * 32;
    {
      int row = t >> 4, c16 = t & 15;      // K: 32 rows x 16 slots
      int sc = c16 ^ (row & 15);
      __builtin_amdgcn_global_load_lds(
          (const AS1 void*)(kp + (size_t)(kc0 + row) * D_ + sc * 8),
          (AS3 void*)&Ks[buf][(size_t)t * 8], 16, 0, 0);
    }
    {
      int row = t >> 2, c16 = t & 3;       // V: 128 rows x 4 slots
      int sc = c16 ^ (row & 3);
      __builtin_amdgcn_global_load_lds(
          (const AS1 void*)(vp + (size_t)row * L_ + kc0 + sc * 8),
          (AS3 void*)&Vs[buf][(size_t)t * 8], 16, 0, 0);
    }
  };

  stage(0, 0);
  u64 mw_cur[2] = {0, 0}, mw_nxt[2] = {0, 0};
  if (!full) { mw_cur[0] = mrow0[0]; mw_cur[1] = mrow1[0]; }
  __syncthreads();   // drains Q stage + chunk-0 stage

  for (int ch = 0; ch < 8; ++ch) {
    int cur = ch & 1;
    if (ch < 7) stage(cur ^ 1, ch + 1);         // prefetch next chunk
    if (!full && (ch & 1) == 0 && (ch >> 1) + 1 < 4) {
      mw_nxt[0] = mrow0[(ch >> 1) + 1];
      mw_nxt[1] = mrow1[(ch >> 1) + 1];
    }

    const ushort_t* ks = &Ks[cur][0];
    const ushort_t* vs = &Vs[cur][0];

    bf16x8 paf[2][2];
    #pragma unroll
    for (int tl = 0; tl < 2; ++tl) {
      // S^T: sacc[r] = S[q][kvb + ch*32 + crow(r,hi2)]
      f32x16 sacc;
      #pragma unroll
      for (int r = 0; r < 16; ++r) sacc[r] = 0.f;
      __builtin_amdgcn_s_setprio(1);
      #pragma unroll
      for (int dt = 0; dt < 8; ++dt) {
        int c16 = (dt * 2 + hi2) ^ (lo32 & 15);
        bf16x8 kf = *(const bf16x8*)&ks[lo32 * 128 + c16 * 8];
        bf16x8 qd;
        if (tl == 0) qd = qf0[dt];
        else         qd = *(const bf16x8*)&Qs[wv][lo32 * 128 + c16 * 8];
        sacc = __builtin_amdgcn_mfma_f32_32x32x16_bf16(kf, qd, sacc, 0, 0, 0);
      }
      __builtin_amdgcn_s_setprio(0);

      uint_t mbits = full ? 0xffffffffu : (uint_t)(mw_cur[tl] >> ((ch & 1) * 32));
      float sv[16];
      #pragma unroll
      for (int r = 0; r < 16; ++r) {
        int shift = (r & 3) + 8 * (r >> 2) + hi2 * 4;
        sv[r] = ((mbits >> shift) & 1u) ? sacc[r] : NEGINF;
      }

      // in-lane max tree + 1 cross-lane
      float a8[8];
      #pragma unroll
      for (int j = 0; j < 8; ++j) a8[j] = fmaxf(sv[2 * j], sv[2 * j + 1]);
      #pragma unroll
      for (int j = 0; j < 4; ++j) a8[j] = fmaxf(a8[j], a8[j + 4]);
      float pmax = fmaxf(fmaxf(a8[0], a8[1]), fmaxf(a8[2], a8[3]));
      pmax = fmaxf(pmax, __shfl_xor(pmax, 32));

      // defer-max (T13)
      if (__any(pmax > m_run[tl] + THR_)) {
        float mn = fmaxf(m_run[tl], pmax);
        float corr = __expf(m_run[tl] - mn);
        l_run[tl] *= corr;
        m_run[tl] = mn;
        float cT[16];
        #pragma unroll
        for (int r = 0; r < 16; ++r)
          cT[r] = __shfl(corr, (r & 3) + 8 * (r >> 2) + hi2 * 4);
        #pragma unroll
        for (int dt = 0; dt < 4; ++dt)
          #pragma unroll
          for (int r = 0; r < 16; ++r) acc[tl][dt][r] *= cT[r];
      }

      // P = exp(S - m_run); row-sum
      float p[16];
      #pragma unroll
      for (int r = 0; r < 16; ++r) p[r] = __expf(sv[r] - m_run[tl]);
      float s8[8];
      #pragma unroll
      for (int j = 0; j < 8; ++j) s8[j] = p[2 * j] + p[2 * j + 1];
      #pragma unroll
      for (int j = 0; j < 4; ++j) s8[j] = s8[j] + s8[j + 4];
      float rs = (s8[0] + s8[1]) + (s8[2] + s8[3]);
      rs += __shfl_xor(rs, 32);
      l_run[tl] += rs;

      // pack P; half-swap to build PV A-frags (R6/R8-verified)
      uint_t ow[8];
      #pragma unroll
      for (int j = 0; j < 8; ++j)
        ow[j] = (uint_t)f2bf(p[2 * j]) | ((uint_t)f2bf(p[2 * j + 1]) << 16);
      uint_t pw[8];
      #pragma unroll
      for (int j = 0; j < 8; ++j) pw[j] = __shfl_xor(ow[j], 32);
      u32x4 pa0 = (u32x4){hi2 ? pw[2] : ow[0], hi2 ? pw[3] : ow[1],
                          hi2 ? ow[2] : pw[0], hi2 ? ow[3] : pw[1]};
      u32x4 pa1 = (u32x4){hi2 ? pw[6] : ow[4], hi2 ? pw[7] : ow[5],
                          hi2 ? ow[6] : pw[4], hi2 ? ow[7] : pw[5]};
      paf[tl][0] = __builtin_bit_cast(bf16x8, pa0);
      paf[tl][1] = __builtin_bit_cast(bf16x8, pa1);
    }

    // PV: V frags loaded once, shared by both tiles
    __builtin_amdgcn_s_setprio(1);
    #pragma unroll
    for (int dt = 0; dt < 4; ++dt) {
      int vd = dt * 32 + lo32;
      int c16a = hi2 ^ (vd & 3);
      int c16b = (2 + hi2) ^ (vd & 3);
      bf16x8 vfa = *(const bf16x8*)&vs[vd * 32 + c16a * 8];
      bf16x8 vfb = *(const bf16x8*)&vs[vd * 32 + c16b * 8];
      acc[0][dt] = __builtin_amdgcn_mfma_f32_32x32x16_bf16(paf[0][0], vfa, acc[0][dt], 0, 0, 0);
      acc[0][dt] = __builtin_amdgcn_mfma_f32_32x32x16_bf16(paf[0][1], vfb, acc[0][dt], 0, 0, 0);
      acc[1][dt] = __builtin_amdgcn_mfma_f32_32x32x16_bf16(paf[1][0], vfa, acc[1][dt], 0, 0, 0);
      acc[1][dt] = __builtin_amdgcn_mfma_f32_32x32x16_bf16(paf[1][1], vfb, acc[1][dt], 0, 0, 0);
    }
    __builtin_amdgcn_s_setprio(0);
    if (ch & 1) { mw_cur[0] = mw_nxt[0]; mw_cur[1] = mw_nxt[1]; }
    __syncthreads();
  }

  // epilogue: partials for both tiles. (m,l) on hi2==0 lanes; N bf16.
  ushort_t* np = (quar == 0) ? np0 : (quar == 1) ? np1 : (quar == 2) ? np2 : np3;
  #pragma unroll
  for (int tl = 0; tl < 2; ++tl) {
    int qb2 = qw + tl * 256;
    if (hi2 == 0) {
      size_t row = (size_t)bh * L_ + qb2 + lo32;
      float2 v2 = make_float2(m_run[tl], l_run[tl]);
      *(float2*)(ml + ((size_t)quar * BH_ * L_ + row) * 2) = v2;
    }
    #pragma unroll
    for (int dt = 0; dt < 4; ++dt)
      #pragma unroll
      for (int r = 0; r < 16; ++r) {
        int qrow = qb2 + (r & 3) + 8 * (r >> 2) + hi2 * 4;
        np[((size_t)bh * L_ + qrow) * D_ + dt * 32 + lo32] = f2bf(acc[tl][dt][r]);
      }
  }
}

// ------------------------------------------------- split-K combine (4-way)
__global__ __launch_bounds__(256)
void combine(const ushort_t* __restrict__ np0, const ushort_t* __restrict__ np1,
             const ushort_t* __restrict__ np2, const ushort_t* __restrict__ np3,
             const float* __restrict__ ml, ushort_t* __restrict__ obf) {
  int bh = blockIdx.x;
  int b = bh / H_, h = bh - b * H_;
  if (h == 0) return;                       // eye head written directly
  int t = threadIdx.x;
  int qi = t >> 4, di = t & 15;             // 16 q-rows x 16 d-groups of 8
  int qq = blockIdx.y * 16 + qi;
  size_t row = (size_t)bh * L_ + qq;
  float2 mlv[4];
  #pragma unroll
  for (int s = 0; s < 4; ++s)
    mlv[s] = *(const float2*)(ml + ((size_t)s * BH_ * L_ + row) * 2);
  float M = fmaxf(fmaxf(mlv[0].x, mlv[1].x), fmaxf(mlv[2].x, mlv[3].x));
  float w[4], lsum = 0.f;
  #pragma unroll
  for (int s = 0; s < 4; ++s) { w[s] = __expf(mlv[s].x - M); lsum += w[s] * mlv[s].y; }
  float inv = 1.f / lsum;
  bf16x8 n0 = *(const bf16x8*)(np0 + row * D_ + di * 8);
  bf16x8 n1 = *(const bf16x8*)(np1 + row * D_ + di * 8);
  bf16x8 n2 = *(const bf16x8*)(np2 + row * D_ + di * 8);
  bf16x8 n3 = *(const bf16x8*)(np3 + row * D_ + di * 8);
  ushort_t o[8];
  #pragma unroll
  for (int j = 0; j < 8; ++j)
    o[j] = f2bf((w[0] * bf2f((ushort_t)n0[j]) + w[1] * bf2f((ushort_t)n1[j]) +
                 w[2] * bf2f((ushort_t)n2[j]) + w[3] * bf2f((ushort_t)n3[j])) * inv);
  *(bf16x8*)(obf + ((size_t)b * L_ + qq) * C_ + h * D_ + di * 8) = *(bf16x8*)o;
}

// ---------------------------------------------------------------- launcher
extern "C" void kernel_launch(void* const* d_in, const int* in_sizes, int n_in,
                              void* d_out, int out_size, void* d_ws, size_t ws_size,
                              hipStream_t stream) {
  const float* x     = (const float*)d_in[0];
  const int*   adj   = (const int*)d_in[1];
  const int*   dist  = (const int*)d_in[2];
  const float* wqkv  = (const float*)d_in[3];
  const float* wproj = (const float*)d_in[4];
  float* out = (float*)d_out;
  char* ws = (char*)d_ws;

  const size_t SZ_X   = (size_t)B_ * L_ * C_ * 2;        // 12.6 MB (== SZ_QKV)
  const size_t SZ_WQ  = (size_t)3 * C_ * C_ * 2;
  const size_t SZ_WP  = (size_t)C_ * C_ * 2;
  const size_t SZ_QKV = (size_t)BH_ * L_ * D_ * 2;       // 12.6 MB
  const size_t SZ_MSK = (size_t)B_ * L_ * 16 * 8;        // 1 MB
  const size_t SZ_ML  = (size_t)4 * BH_ * L_ * 2 * 4;    // 1.6 MB
  size_t off = 0;
  ushort_t* xbf  = (ushort_t*)(ws + off); off += SZ_X;   // reused as np0 post-GEMM
  ushort_t* wqb  = (ushort_t*)(ws + off); off += SZ_WQ;
  ushort_t* wpb  = (ushort_t*)(ws + off); off += SZ_WP;
  ushort_t* qb   = (ushort_t*)(ws + off); off += SZ_QKV;
  ushort_t* kb   = (ushort_t*)(ws + off); off += SZ_QKV;
  ushort_t* vTb  = (ushort_t*)(ws + off); off += SZ_QKV;
  ushort_t* vb   = (ushort_t*)(ws + off); off += SZ_QKV;
  ushort_t* ob   = (ushort_t*)(ws + off); off += SZ_X;
  u64* a1p = (u64*)(ws + off); off += SZ_MSK;
  u64* a2p = (u64*)(ws + off); off += SZ_MSK;
  u64* d2p = (u64*)(ws + off); off += SZ_MSK;
  u64* d3p = (u64*)(ws + off); off += SZ_MSK;
  ushort_t* np1 = (ushort_t*)(ws + off); off += SZ_QKV;  // partial N quarter 1
  ushort_t* np2 = (ushort_t*)(ws + off); off += SZ_QKV;  // partial N quarter 2
  ushort_t* np3 = (ushort_t*)(ws + off); off += SZ_QKV;  // partial N quarter 3
  float*    mlb = (float*)(ws + off); off += SZ_ML;      // (m,l)[4][BH][L]
  ushort_t* np0 = xbf;                                   // partial N quarter 0
  (void)ws_size; (void)n_in; (void)in_sizes; (void)out_size;

  cvt_f32_bf16<<<(B_ * L_ * C_ / 8 + 255) / 256, 256, 0, stream>>>(x, xbf, B_ * L_ * C_ / 8);
  cvt_f32_bf16<<<(3 * C_ * C_ / 8 + 255) / 256, 256, 0, stream>>>(wqkv, wqb, 3 * C_ * C_ / 8);
  cvt_f32_bf16<<<(C_ * C_ / 8 + 255) / 256, 256, 0, stream>>>(wproj, wpb, C_ * C_ / 8);
  pack_masks<<<dim3(L_, B_), 256, 0, stream>>>(adj, dist, a1p, d2p, d3p);
  hop2<<<B_ * L_ / 64, 64, 0, stream>>>(a1p, a2p);
  // qkv = x @ wqkv^T  (M=8192, N=2304, K=768), nwg=1152 (%8==0)
  gemm_bt<0><<<dim3(3 * C_ / 128, B_ * L_ / 128), 256, 0, stream>>>(
      xbf, wqb, 3 * C_, C_, qb, kb, vTb, vb, nullptr);
  // attention split-K=4: 8-wave blocks, 2 q-tiles/wave (512 q-rows/block)
  attn_kernel<<<dim3(BH_, L_ / 512, 4), 512, 0, stream>>>(
      qb, kb, vTb, vb, ob, np0, np1, np2, np3, mlb, a1p, a2p, d2p, d3p);
  combine<<<dim3(BH_, L_ / 16), 256, 0, stream>>>(np0, np1, np2, np3, mlb, ob);
  // out = O @ wproj^T  (M=8192, N=768, K=768), nwg=384 (%8==0)
  gemm_bt<1><<<dim3(C_ / 128, B_ * L_ / 128), 256, 0, stream>>>(
      ob, wpb, C_, C_, nullptr, nullptr, nullptr, nullptr, out);
}

// Round 17
// 179.891 us; speedup vs baseline: 1.1206x; 1.1206x over previous
//
#include <hip/hip_runtime.h>

typedef unsigned short ushort_t;
typedef unsigned int uint_t;
typedef unsigned long long u64;
typedef __attribute__((ext_vector_type(8))) short bf16x8;
typedef __attribute__((ext_vector_type(4))) float f32x4;
typedef __attribute__((ext_vector_type(16))) float f32x16;
typedef __attribute__((ext_vector_type(4))) uint_t u32x4;

#define B_ 8
#define L_ 1024
#define C_ 768
#define H_ 6
#define D_ 128
#define BH_ 48
#define NEGINF (-1e9f)
#define THR_ 8.0f

#define AS1 __attribute__((address_space(1)))
#define AS3 __attribute__((address_space(3)))

// round-to-nearest-even f32 -> bf16
__device__ __forceinline__ ushort_t f2bf(float f) {
  uint_t u = __builtin_bit_cast(uint_t, f);
  u += 0x7fffu + ((u >> 16) & 1u);
  return (ushort_t)(u >> 16);
}
__device__ __forceinline__ float bf2f(ushort_t s) {
  uint_t u = ((uint_t)s) << 16;
  return __builtin_bit_cast(float, u);
}

// ---------------------------------------------------------------- converts
__global__ void cvt_f32_bf16(const float* __restrict__ in, ushort_t* __restrict__ out, int n8) {
  int i = blockIdx.x * 256 + threadIdx.x;
  if (i >= n8) return;
  const float4* p = (const float4*)in + (size_t)i * 2;
  float4 a = p[0], b = p[1];
  uint4 r;
  r.x = (uint_t)f2bf(a.x) | ((uint_t)f2bf(a.y) << 16);
  r.y = (uint_t)f2bf(a.z) | ((uint_t)f2bf(a.w) << 16);
  r.z = (uint_t)f2bf(b.x) | ((uint_t)f2bf(b.y) << 16);
  r.w = (uint_t)f2bf(b.z) | ((uint_t)f2bf(b.w) << 16);
  ((uint4*)out)[i] = r;
}

// ------------------------------------------------- bit-pack a1 / d<=2 / d<=3
__global__ __launch_bounds__(256)
void pack_masks(const int* __restrict__ adj, const int* __restrict__ dist,
                u64* __restrict__ a1p, u64* __restrict__ d2p, u64* __restrict__ d3p) {
  int l = blockIdx.x, b = blockIdx.y, t = threadIdx.x;
  size_t base = ((size_t)b * L_ + l) * L_;
  size_t rb = ((size_t)b * L_ + l) * 16;
  #pragma unroll
  for (int it = 0; it < 4; ++it) {
    int c = it * 256 + t;
    int av = adj[base + c];
    int dv = dist[base + c];
    u64 m1 = __ballot((av > 0) || (c == l));
    u64 m2 = __ballot(dv <= 2);
    u64 m3 = __ballot(dv <= 3);
    if ((t & 63) == 0) {
      int w = it * 4 + (t >> 6);
      a1p[rb + w] = m1; d2p[rb + w] = m2; d3p[rb + w] = m3;
    }
  }
}

// ------------------------------------------------- 2-hop closure (bit OR)
__global__ __launch_bounds__(64)
void hop2(const u64* __restrict__ a1p, u64* __restrict__ a2p) {
  int tid = blockIdx.x * 64 + threadIdx.x;   // 0..8191 = (b,l)
  int b = tid >> 10;
  size_t rb = (size_t)tid * 16;
  u64 row[16], acc[16];
  #pragma unroll
  for (int j = 0; j < 16; ++j) { row[j] = a1p[rb + j]; acc[j] = 0ULL; }
  bool done = false;
  #pragma unroll
  for (int mw = 0; mw < 16; ++mw) {
    if (done) continue;
    u64 bits = row[mw];
    while (bits) {
      int tz = __builtin_ctzll(bits); bits &= bits - 1;
      const u64* src = a1p + (((size_t)b << 10) + (mw << 6) + tz) * 16;
      u64 band = ~0ULL;
      #pragma unroll
      for (int j = 0; j < 16; ++j) { acc[j] |= src[j]; band &= acc[j]; }
      if (band == ~0ULL) { done = true; break; }
    }
  }
  #pragma unroll
  for (int j = 0; j < 16; ++j) a2p[rb + j] = acc[j];
}

// ------------------------------------------------- bf16 GEMM  C = A @ B^T
// 128x128 tile, BK=64, T2 both-sides XOR swizzle, bijective XCD swizzle.
// EPI==0 epilogue is BLOCK-UNIFORM in sec (n-tiles 128-wide, 768%128==0).
template<int EPI>
__global__ __launch_bounds__(256)
void gemm_bt(const ushort_t* __restrict__ A, const ushort_t* __restrict__ Bm,
             int N, int K,
             ushort_t* __restrict__ qo, ushort_t* __restrict__ ko,
             ushort_t* __restrict__ vTo, ushort_t* __restrict__ vo,
             float* __restrict__ fo) {
  __shared__ __align__(16) ushort_t As[128 * 64];   // 16 KB
  __shared__ __align__(16) ushort_t Bs[128 * 64];   // 16 KB
  int t = threadIdx.x;
  int lane = t & 63, lo = lane & 15, hi = lane >> 4;
  int wv = t >> 6, wm = wv >> 1, wn = wv & 1;

  int gx = gridDim.x;
  int nwg = gx * gridDim.y;
  int orig = blockIdx.y * gx + blockIdx.x;
  int cpx = nwg >> 3;
  int wg = (orig & 7) * cpx + (orig >> 3);
  int n0 = (wg % gx) * 128;
  int m0 = (wg / gx) * 128;

  f32x4 acc[4][4];
  #pragma unroll
  for (int mi = 0; mi < 4; ++mi)
    #pragma unroll
    for (int ni = 0; ni < 4; ++ni) acc[mi][ni] = (f32x4){0.f, 0.f, 0.f, 0.f};

  for (int kt = 0; kt < K; kt += 64) {
    #pragma unroll
    for (int i = 0; i < 4; ++i) {
      int u = i * 256 + t;                 // 0..1023
      int row = u >> 3, c16 = u & 7;
      int sc = c16 ^ (row & 7);
      __builtin_amdgcn_global_load_lds(
          (const AS1 void*)(A + ((size_t)(m0 + row) * K + kt + sc * 8)),
          (AS3 void*)&As[(size_t)u * 8], 16, 0, 0);
      __builtin_amdgcn_global_load_lds(
          (const AS1 void*)(Bm + ((size_t)(n0 + row) * K + kt + sc * 8)),
          (AS3 void*)&Bs[(size_t)u * 8], 16, 0, 0);
    }
    __syncthreads();
    #pragma unroll
    for (int kks = 0; kks < 2; ++kks) {
      bf16x8 af[4], bfr[4];
      #pragma unroll
      for (int mi = 0; mi < 4; ++mi) {
        int r = wm * 64 + mi * 16 + lo;
        af[mi] = *(const bf16x8*)&As[r * 64 + (((kks * 4 + hi) ^ (r & 7)) * 8)];
      }
      #pragma unroll
      for (int ni = 0; ni < 4; ++ni) {
        int r = wn * 64 + ni * 16 + lo;
        bfr[ni] = *(const bf16x8*)&Bs[r * 64 + (((kks * 4 + hi) ^ (r & 7)) * 8)];
      }
      #pragma unroll
      for (int mi = 0; mi < 4; ++mi)
        #pragma unroll
        for (int ni = 0; ni < 4; ++ni)
          acc[mi][ni] = __builtin_amdgcn_mfma_f32_16x16x32_bf16(af[mi], bfr[ni], acc[mi][ni], 0, 0, 0);
    }
    __syncthreads();
  }

  // epilogue. D layout: col = lane&15, row = (lane>>4)*4 + j  [m89-verified]
  if (EPI == 1) {
    #pragma unroll
    for (int mi = 0; mi < 4; ++mi) {
      int rbase = m0 + wm * 64 + mi * 16 + hi * 4;
      #pragma unroll
      for (int ni = 0; ni < 4; ++ni) {
        int c = n0 + wn * 64 + ni * 16 + lo;
        f32x4 v = acc[mi][ni];
        #pragma unroll
        for (int j = 0; j < 4; ++j)
          fo[(size_t)(rbase + j) * N + c] = v[j];
      }
    }
    return;
  }
  // EPI == 0: block-uniform section
  int sec = n0 / 768;
  if (sec < 2) {
    #pragma unroll
    for (int mi = 0; mi < 4; ++mi) {
      int rbase = m0 + wm * 64 + mi * 16 + hi * 4;
      #pragma unroll
      for (int ni = 0; ni < 4; ++ni) {
        int cc = n0 - sec * 768 + wn * 64 + ni * 16 + lo;
        int hh = cc >> 7, dd = cc & 127;
        f32x4 v = acc[mi][ni];
        #pragma unroll
        for (int j = 0; j < 4; ++j) {
          int r = rbase + j;
          int b = r >> 10, l = r & 1023;
          size_t bh = (size_t)(b * H_ + hh);
          if (sec == 0) qo[(bh * L_ + l) * D_ + dd] = f2bf(v[j] * 0.08838834764831845f);
          else          ko[(bh * L_ + l) * D_ + dd] = f2bf(v[j]);
        }
      }
    }
    return;
  }
  // sec == 2: V third. h is block-uniform.
  int hh = (n0 - 1536) >> 7;
  int b = m0 >> 10, l0 = m0 & 1023;
  size_t bh = (size_t)(b * H_ + hh);
  if (hh == 0) {
    // eye head: only row-major v needed
    #pragma unroll
    for (int mi = 0; mi < 4; ++mi) {
      int lb = wm * 64 + mi * 16 + hi * 4;
      #pragma unroll
      for (int ni = 0; ni < 4; ++ni) {
        int dd = wn * 64 + ni * 16 + lo;
        f32x4 v = acc[mi][ni];
        #pragma unroll
        for (int j = 0; j < 4; ++j)
          vo[(bh * L_ + l0 + lb + j) * D_ + dd] = f2bf(v[j]);
      }
    }
    return;
  }
  // h != 0: only vT needed. LDS transpose, XOR (dd&7)<<4 both sides.
  #pragma unroll
  for (int mi = 0; mi < 4; ++mi) {
    int lb = wm * 64 + mi * 16 + hi * 4;
    #pragma unroll
    for (int ni = 0; ni < 4; ++ni) {
      int dd = wn * 64 + ni * 16 + lo;
      ushort_t* base = (dd < 64) ? As : Bs;
      f32x4 v = acc[mi][ni];
      #pragma unroll
      for (int j = 0; j < 4; ++j) {
        int byte = (((dd & 63) * 256 + (lb + j) * 2)) ^ ((dd & 7) << 4);
        *(ushort_t*)((char*)base + byte) = f2bf(v[j]);
      }
    }
  }
  __syncthreads();
  #pragma unroll
  for (int i = 0; i < 8; ++i) {
    int u = i * 256 + t;            // 2048 chunks: dd 0..127 x 16 16B-chunks
    int ddl = u >> 4, c16 = u & 15;
    const ushort_t* base = (ddl < 64) ? As : Bs;
    int byte = (((ddl & 63) * 256 + c16 * 16)) ^ ((ddl & 7) << 4);
    bf16x8 val = *(const bf16x8*)((const char*)base + byte);
    *(bf16x8*)(vTo + (bh * D_ + ddl) * L_ + l0 + c16 * 8) = val;
  }
}

// ------------------------------------------------- flash attention, split-K=4
// 8 waves / block, 256 q-rows (32/wave); kv quarter per blockIdx.z; KVBLK=32,
// 8 chunks per block (128 KB staged). Partials: N (bf16) + (m,l) f32 per
// quarter; combine merges 4. (R13/R15-verified optimum; R14's 16-wave and
// R16's 2-tile variants both hit VGPR cliffs -> spills, reverted.)
__global__ __launch_bounds__(512)
void attn_kernel(const ushort_t* __restrict__ q, const ushort_t* __restrict__ k,
                 const ushort_t* __restrict__ vT, const ushort_t* __restrict__ v,
                 ushort_t* __restrict__ obf,
                 ushort_t* __restrict__ np0, ushort_t* __restrict__ np1,
                 ushort_t* __restrict__ np2, ushort_t* __restrict__ np3,
                 float* __restrict__ ml,
                 const u64* __restrict__ a1p, const u64* __restrict__ a2p,
                 const u64* __restrict__ d2p, const u64* __restrict__ d3p) {
  __shared__ __align__(16) ushort_t Ks[2][32 * 128];   // [krow][d]  8 KB x2
  __shared__ __align__(16) ushort_t Vs[2][128 * 32];   // [d][kcol]  8 KB x2
  int t = threadIdx.x;
  int lane = t & 63, lo32 = lane & 31, hi2 = (lane >> 5) & 1, wv = t >> 6;
  int bh = blockIdx.x, qt = blockIdx.y, quar = blockIdx.z;
  int b = bh / H_, h = bh - b * H_;
  int qbase = qt * 256;
  int qw = qbase + wv * 32;
  int kvb = quar * 256;

  if (h == 0) {
    if (quar) return;
    // eye mask: out = v[l]  (h*D_ == 0 in output)
    const ushort_t* vp0 = v + ((size_t)bh * L_ + qbase) * D_;
    ushort_t* op0 = obf + ((size_t)b * L_ + qbase) * C_;
    #pragma unroll
    for (int it = 0; it < 8; ++it) {
      int u = it * 512 + t;
      int r = u >> 4, c = (u & 15) * 8;
      *(bf16x8*)(op0 + (size_t)r * C_ + c) = *(const bf16x8*)(vp0 + (size_t)r * D_ + c);
    }
    return;
  }

  const ushort_t* qp = q + (size_t)bh * L_ * D_;
  const ushort_t* kp = k + (size_t)bh * L_ * D_ + (size_t)kvb * D_;
  const ushort_t* vp = vT + (size_t)bh * D_ * L_ + kvb;

  bf16x8 qf[8];
  #pragma unroll
  for (int dt = 0; dt < 8; ++dt)
    qf[dt] = *(const bf16x8*)(qp + (size_t)(qw + lo32) * D_ + dt * 16 + hi2 * 8);

  const u64* mp = (h == 1) ? a1p : (h == 2) ? a2p : (h == 3) ? d2p : d3p;
  bool full = (h == 5);
  const u64* mrow = mp + ((size_t)b * L_ + qw + lo32) * 16 + quar * 4;

  float m_run = NEGINF, l_run = 0.f;
  f32x16 acc[4];
  #pragma unroll
  for (int dt = 0; dt < 4; ++dt)
    #pragma unroll
    for (int r = 0; r < 16; ++r) acc[dt][r] = 0.f;

  // stage one 32-col K/V chunk: 2 global_load_lds per thread (512 threads)
  auto stage = [&](int buf, int ch) {
    int kc0 = ch * 32;
    {
      int row = t >> 4, c16 = t & 15;      // K: 32 rows x 16 slots
      int sc = c16 ^ (row & 15);
      __builtin_amdgcn_global_load_lds(
          (const AS1 void*)(kp + (size_t)(kc0 + row) * D_ + sc * 8),
          (AS3 void*)&Ks[buf][(size_t)t * 8], 16, 0, 0);
    }
    {
      int row = t >> 2, c16 = t & 3;       // V: 128 rows x 4 slots
      int sc = c16 ^ (row & 3);
      __builtin_amdgcn_global_load_lds(
          (const AS1 void*)(vp + (size_t)row * L_ + kc0 + sc * 8),
          (AS3 void*)&Vs[buf][(size_t)t * 8], 16, 0, 0);
    }
  };

  stage(0, 0);
  u64 mw_cur = full ? 0ULL : mrow[0];
  u64 mw_nxt = 0ULL;
  __syncthreads();

  for (int ch = 0; ch < 8; ++ch) {
    int cur = ch & 1;
    if (ch < 7) stage(cur ^ 1, ch + 1);         // prefetch next chunk
    if (!full && (ch & 1) == 0 && (ch >> 1) + 1 < 4)
      mw_nxt = mrow[(ch >> 1) + 1];

    const ushort_t* ks = &Ks[cur][0];
    const ushort_t* vs = &Vs[cur][0];
    uint_t mbits = full ? 0xffffffffu : (uint_t)(mw_cur >> ((ch & 1) * 32));

    // S^T: sacc[r] = S[q=lo32][kvb + ch*32 + crow(r,hi2)]
    f32x16 sacc;
    #pragma unroll
    for (int r = 0; r < 16; ++r) sacc[r] = 0.f;
    __builtin_amdgcn_s_setprio(1);
    #pragma unroll
    for (int dt = 0; dt < 8; ++dt) {
      int c16 = (dt * 2 + hi2) ^ (lo32 & 15);
      bf16x8 kf = *(const bf16x8*)&ks[lo32 * 128 + c16 * 8];
      sacc = __builtin_amdgcn_mfma_f32_32x32x16_bf16(kf, qf[dt], sacc, 0, 0, 0);
    }
    __builtin_amdgcn_s_setprio(0);

    float sv[16];
    #pragma unroll
    for (int r = 0; r < 16; ++r) {
      int shift = (r & 3) + 8 * (r >> 2) + hi2 * 4;
      sv[r] = ((mbits >> shift) & 1u) ? sacc[r] : NEGINF;
    }

    // in-lane max tree + 1 cross-lane
    float a8[8];
    #pragma unroll
    for (int j = 0; j < 8; ++j) a8[j] = fmaxf(sv[2 * j], sv[2 * j + 1]);
    #pragma unroll
    for (int j = 0; j < 4; ++j) a8[j] = fmaxf(a8[j], a8[j + 4]);
    float pmax = fmaxf(fmaxf(a8[0], a8[1]), fmaxf(a8[2], a8[3]));
    pmax = fmaxf(pmax, __shfl_xor(pmax, 32));

    // defer-max (T13)
    if (__any(pmax > m_run + THR_)) {
      float mn = fmaxf(m_run, pmax);
      float corr = __expf(m_run - mn);
      l_run *= corr;
      m_run = mn;
      float cT[16];
      #pragma unroll
      for (int r = 0; r < 16; ++r)
        cT[r] = __shfl(corr, (r & 3) + 8 * (r >> 2) + hi2 * 4);
      #pragma unroll
      for (int dt = 0; dt < 4; ++dt)
        #pragma unroll
        for (int r = 0; r < 16; ++r) acc[dt][r] *= cT[r];
    }

    // P = exp(S - m_run); row-sum
    float p[16];
    #pragma unroll
    for (int r = 0; r < 16; ++r) p[r] = __expf(sv[r] - m_run);
    float s8[8];
    #pragma unroll
    for (int j = 0; j < 8; ++j) s8[j] = p[2 * j] + p[2 * j + 1];
    #pragma unroll
    for (int j = 0; j < 4; ++j) s8[j] = s8[j] + s8[j + 4];
    float rs = (s8[0] + s8[1]) + (s8[2] + s8[3]);
    rs += __shfl_xor(rs, 32);
    l_run += rs;

    // pack P; half-swap to build PV A-frags (R6/R8-verified)
    uint_t ow[8];
    #pragma unroll
    for (int j = 0; j < 8; ++j)
      ow[j] = (uint_t)f2bf(p[2 * j]) | ((uint_t)f2bf(p[2 * j + 1]) << 16);
    uint_t pw[8];
    #pragma unroll
    for (int j = 0; j < 8; ++j) pw[j] = __shfl_xor(ow[j], 32);
    u32x4 pa0 = (u32x4){hi2 ? pw[2] : ow[0], hi2 ? pw[3] : ow[1],
                        hi2 ? ow[2] : pw[0], hi2 ? ow[3] : pw[1]};
    u32x4 pa1 = (u32x4){hi2 ? pw[6] : ow[4], hi2 ? pw[7] : ow[5],
                        hi2 ? ow[6] : pw[4], hi2 ? ow[7] : pw[5]};
    bf16x8 paf0 = __builtin_bit_cast(bf16x8, pa0);
    bf16x8 paf1 = __builtin_bit_cast(bf16x8, pa1);

    // PV: paf0 ~ kv 0..15, paf1 ~ kv 16..31 of the chunk
    __builtin_amdgcn_s_setprio(1);
    #pragma unroll
    for (int dt = 0; dt < 4; ++dt) {
      int vd = dt * 32 + lo32;
      int c16a = hi2 ^ (vd & 3);
      int c16b = (2 + hi2) ^ (vd & 3);
      bf16x8 vfa = *(const bf16x8*)&vs[vd * 32 + c16a * 8];
      bf16x8 vfb = *(const bf16x8*)&vs[vd * 32 + c16b * 8];
      acc[dt] = __builtin_amdgcn_mfma_f32_32x32x16_bf16(paf0, vfa, acc[dt], 0, 0, 0);
      acc[dt] = __builtin_amdgcn_mfma_f32_32x32x16_bf16(paf1, vfb, acc[dt], 0, 0, 0);
    }
    __builtin_amdgcn_s_setprio(0);
    if (ch & 1) mw_cur = mw_nxt;
    __syncthreads();
  }

  // epilogue: write partials. (m,l) per q-row (hi2==0 lanes); N unnormalized bf16.
  if (hi2 == 0) {
    size_t row = (size_t)bh * L_ + qw + lo32;
    float2 v2 = make_float2(m_run, l_run);
    *(float2*)(ml + ((size_t)quar * BH_ * L_ + row) * 2) = v2;
  }
  ushort_t* np = (quar == 0) ? np0 : (quar == 1) ? np1 : (quar == 2) ? np2 : np3;
  #pragma unroll
  for (int dt = 0; dt < 4; ++dt)
    #pragma unroll
    for (int r = 0; r < 16; ++r) {
      int qrow = qw + (r & 3) + 8 * (r >> 2) + hi2 * 4;
      np[((size_t)bh * L_ + qrow) * D_ + dt * 32 + lo32] = f2bf(acc[dt][r]);
    }
}

// ------------------------------------------------- split-K combine (4-way)
__global__ __launch_bounds__(256)
void combine(const ushort_t* __restrict__ np0, const ushort_t* __restrict__ np1,
             const ushort_t* __restrict__ np2, const ushort_t* __restrict__ np3,
             const float* __restrict__ ml, ushort_t* __restrict__ obf) {
  int bh = blockIdx.x;
  int b = bh / H_, h = bh - b * H_;
  if (h == 0) return;                       // eye head written directly
  int t = threadIdx.x;
  int qi = t >> 4, di = t & 15;             // 16 q-rows x 16 d-groups of 8
  int qq = blockIdx.y * 16 + qi;
  size_t row = (size_t)bh * L_ + qq;
  float2 mlv[4];
  #pragma unroll
  for (int s = 0; s < 4; ++s)
    mlv[s] = *(const float2*)(ml + ((size_t)s * BH_ * L_ + row) * 2);
  float M = fmaxf(fmaxf(mlv[0].x, mlv[1].x), fmaxf(mlv[2].x, mlv[3].x));
  float w[4], lsum = 0.f;
  #pragma unroll
  for (int s = 0; s < 4; ++s) { w[s] = __expf(mlv[s].x - M); lsum += w[s] * mlv[s].y; }
  float inv = 1.f / lsum;
  bf16x8 n0 = *(const bf16x8*)(np0 + row * D_ + di * 8);
  bf16x8 n1 = *(const bf16x8*)(np1 + row * D_ + di * 8);
  bf16x8 n2 = *(const bf16x8*)(np2 + row * D_ + di * 8);
  bf16x8 n3 = *(const bf16x8*)(np3 + row * D_ + di * 8);
  ushort_t o[8];
  #pragma unroll
  for (int j = 0; j < 8; ++j)
    o[j] = f2bf((w[0] * bf2f((ushort_t)n0[j]) + w[1] * bf2f((ushort_t)n1[j]) +
                 w[2] * bf2f((ushort_t)n2[j]) + w[3] * bf2f((ushort_t)n3[j])) * inv);
  *(bf16x8*)(obf + ((size_t)b * L_ + qq) * C_ + h * D_ + di * 8) = *(bf16x8*)o;
}

// ---------------------------------------------------------------- launcher
extern "C" void kernel_launch(void* const* d_in, const int* in_sizes, int n_in,
                              void* d_out, int out_size, void* d_ws, size_t ws_size,
                              hipStream_t stream) {
  const float* x     = (const float*)d_in[0];
  const int*   adj   = (const int*)d_in[1];
  const int*   dist  = (const int*)d_in[2];
  const float* wqkv  = (const float*)d_in[3];
  const float* wproj = (const float*)d_in[4];
  float* out = (float*)d_out;
  char* ws = (char*)d_ws;

  const size_t SZ_X   = (size_t)B_ * L_ * C_ * 2;        // 12.6 MB (== SZ_QKV)
  const size_t SZ_WQ  = (size_t)3 * C_ * C_ * 2;
  const size_t SZ_WP  = (size_t)C_ * C_ * 2;
  const size_t SZ_QKV = (size_t)BH_ * L_ * D_ * 2;       // 12.6 MB
  const size_t SZ_MSK = (size_t)B_ * L_ * 16 * 8;        // 1 MB
  const size_t SZ_ML  = (size_t)4 * BH_ * L_ * 2 * 4;    // 1.6 MB
  size_t off = 0;
  ushort_t* xbf  = (ushort_t*)(ws + off); off += SZ_X;   // reused as np0 post-GEMM
  ushort_t* wqb  = (ushort_t*)(ws + off); off += SZ_WQ;
  ushort_t* wpb  = (ushort_t*)(ws + off); off += SZ_WP;
  ushort_t* qb   = (ushort_t*)(ws + off); off += SZ_QKV;
  ushort_t* kb   = (ushort_t*)(ws + off); off += SZ_QKV;
  ushort_t* vTb  = (ushort_t*)(ws + off); off += SZ_QKV;
  ushort_t* vb   = (ushort_t*)(ws + off); off += SZ_QKV;
  ushort_t* ob   = (ushort_t*)(ws + off); off += SZ_X;
  u64* a1p = (u64*)(ws + off); off += SZ_MSK;
  u64* a2p = (u64*)(ws + off); off += SZ_MSK;
  u64* d2p = (u64*)(ws + off); off += SZ_MSK;
  u64* d3p = (u64*)(ws + off); off += SZ_MSK;
  ushort_t* np1 = (ushort_t*)(ws + off); off += SZ_QKV;  // partial N quarter 1
  ushort_t* np2 = (ushort_t*)(ws + off); off += SZ_QKV;  // partial N quarter 2
  ushort_t* np3 = (ushort_t*)(ws + off); off += SZ_QKV;  // partial N quarter 3
  float*    mlb = (float*)(ws + off); off += SZ_ML;      // (m,l)[4][BH][L]
  ushort_t* np0 = xbf;                                   // partial N quarter 0
  (void)ws_size; (void)n_in; (void)in_sizes; (void)out_size;

  cvt_f32_bf16<<<(B_ * L_ * C_ / 8 + 255) / 256, 256, 0, stream>>>(x, xbf, B_ * L_ * C_ / 8);
  cvt_f32_bf16<<<(3 * C_ * C_ / 8 + 255) / 256, 256, 0, stream>>>(wqkv, wqb, 3 * C_ * C_ / 8);
  cvt_f32_bf16<<<(C_ * C_ / 8 + 255) / 256, 256, 0, stream>>>(wproj, wpb, C_ * C_ / 8);
  pack_masks<<<dim3(L_, B_), 256, 0, stream>>>(adj, dist, a1p, d2p, d3p);
  hop2<<<B_ * L_ / 64, 64, 0, stream>>>(a1p, a2p);
  // qkv = x @ wqkv^T  (M=8192, N=2304, K=768), nwg=1152 (%8==0)
  gemm_bt<0><<<dim3(3 * C_ / 128, B_ * L_ / 128), 256, 0, stream>>>(
      xbf, wqb, 3 * C_, C_, qb, kb, vTb, vb, nullptr);
  // attention split-K=4: 8-wave blocks, 256 q-rows; grid (bh, qt, quarter)
  attn_kernel<<<dim3(BH_, L_ / 256, 4), 512, 0, stream>>>(
      qb, kb, vTb, vb, ob, np0, np1, np2, np3, mlb, a1p, a2p, d2p, d3p);
  combine<<<dim3(BH_, L_ / 16), 256, 0, stream>>>(np0, np1, np2, np3, mlb, ob);
  // out = O @ wproj^T  (M=8192, N=768, K=768), nwg=384 (%8==0)
  gemm_bt<1><<<dim3(C_ / 128, B_ * L_ / 128), 256, 0, stream>>>(
      ob, wpb, C_, C_, nullptr, nullptr, nullptr, nullptr, out);
}

// Round 18
// 175.122 us; speedup vs baseline: 1.1511x; 1.0272x over previous
//
#include <hip/hip_runtime.h>

typedef unsigned short ushort_t;
typedef unsigned int uint_t;
typedef unsigned long long u64;
typedef __attribute__((ext_vector_type(8))) short bf16x8;
typedef __attribute__((ext_vector_type(4))) float f32x4;
typedef __attribute__((ext_vector_type(16))) float f32x16;
typedef __attribute__((ext_vector_type(4))) uint_t u32x4;

#define B_ 8
#define L_ 1024
#define C_ 768
#define H_ 6
#define D_ 128
#define BH_ 48
#define NEGINF (-1e9f)
#define THR_ 8.0f

#define AS1 __attribute__((address_space(1)))
#define AS3 __attribute__((address_space(3)))

// round-to-nearest-even f32 -> bf16
__device__ __forceinline__ ushort_t f2bf(float f) {
  uint_t u = __builtin_bit_cast(uint_t, f);
  u += 0x7fffu + ((u >> 16) & 1u);
  return (ushort_t)(u >> 16);
}
__device__ __forceinline__ float bf2f(ushort_t s) {
  uint_t u = ((uint_t)s) << 16;
  return __builtin_bit_cast(float, u);
}

// ---------------------------------------------------------------- converts
__global__ void cvt_f32_bf16(const float* __restrict__ in, ushort_t* __restrict__ out, int n8) {
  int i = blockIdx.x * 256 + threadIdx.x;
  if (i >= n8) return;
  const float4* p = (const float4*)in + (size_t)i * 2;
  float4 a = p[0], b = p[1];
  uint4 r;
  r.x = (uint_t)f2bf(a.x) | ((uint_t)f2bf(a.y) << 16);
  r.y = (uint_t)f2bf(a.z) | ((uint_t)f2bf(a.w) << 16);
  r.z = (uint_t)f2bf(b.x) | ((uint_t)f2bf(b.y) << 16);
  r.w = (uint_t)f2bf(b.z) | ((uint_t)f2bf(b.w) << 16);
  ((uint4*)out)[i] = r;
}

// ------------------------------------------------- bit-pack a1 / d<=2 / d<=3
__global__ __launch_bounds__(256)
void pack_masks(const int* __restrict__ adj, const int* __restrict__ dist,
                u64* __restrict__ a1p, u64* __restrict__ d2p, u64* __restrict__ d3p) {
  int l = blockIdx.x, b = blockIdx.y, t = threadIdx.x;
  size_t base = ((size_t)b * L_ + l) * L_;
  size_t rb = ((size_t)b * L_ + l) * 16;
  #pragma unroll
  for (int it = 0; it < 4; ++it) {
    int c = it * 256 + t;
    int av = adj[base + c];
    int dv = dist[base + c];
    u64 m1 = __ballot((av > 0) || (c == l));
    u64 m2 = __ballot(dv <= 2);
    u64 m3 = __ballot(dv <= 3);
    if ((t & 63) == 0) {
      int w = it * 4 + (t >> 6);
      a1p[rb + w] = m1; d2p[rb + w] = m2; d3p[rb + w] = m3;
    }
  }
}

// ------------------------------------------------- 2-hop closure (bit OR)
__global__ __launch_bounds__(64)
void hop2(const u64* __restrict__ a1p, u64* __restrict__ a2p) {
  int tid = blockIdx.x * 64 + threadIdx.x;   // 0..8191 = (b,l)
  int b = tid >> 10;
  size_t rb = (size_t)tid * 16;
  u64 row[16], acc[16];
  #pragma unroll
  for (int j = 0; j < 16; ++j) { row[j] = a1p[rb + j]; acc[j] = 0ULL; }
  bool done = false;
  #pragma unroll
  for (int mw = 0; mw < 16; ++mw) {
    if (done) continue;
    u64 bits = row[mw];
    while (bits) {
      int tz = __builtin_ctzll(bits); bits &= bits - 1;
      const u64* src = a1p + (((size_t)b << 10) + (mw << 6) + tz) * 16;
      u64 band = ~0ULL;
      #pragma unroll
      for (int j = 0; j < 16; ++j) { acc[j] |= src[j]; band &= acc[j]; }
      if (band == ~0ULL) { done = true; break; }
    }
  }
  #pragma unroll
  for (int j = 0; j < 16; ++j) a2p[rb + j] = acc[j];
}

// ------------------------------------------------- bf16 GEMM  C = A @ B^T
// 128x128 tile, BK=64, T2 both-sides XOR swizzle, bijective XCD swizzle.
// EPI==0 epilogue is BLOCK-UNIFORM in sec (n-tiles 128-wide, 768%128==0).
template<int EPI>
__global__ __launch_bounds__(256)
void gemm_bt(const ushort_t* __restrict__ A, const ushort_t* __restrict__ Bm,
             int N, int K,
             ushort_t* __restrict__ qo, ushort_t* __restrict__ ko,
             ushort_t* __restrict__ vTo, ushort_t* __restrict__ vo,
             float* __restrict__ fo) {
  __shared__ __align__(16) ushort_t As[128 * 64];   // 16 KB
  __shared__ __align__(16) ushort_t Bs[128 * 64];   // 16 KB
  int t = threadIdx.x;
  int lane = t & 63, lo = lane & 15, hi = lane >> 4;
  int wv = t >> 6, wm = wv >> 1, wn = wv & 1;

  int gx = gridDim.x;
  int nwg = gx * gridDim.y;
  int orig = blockIdx.y * gx + blockIdx.x;
  int cpx = nwg >> 3;
  int wg = (orig & 7) * cpx + (orig >> 3);
  int n0 = (wg % gx) * 128;
  int m0 = (wg / gx) * 128;

  f32x4 acc[4][4];
  #pragma unroll
  for (int mi = 0; mi < 4; ++mi)
    #pragma unroll
    for (int ni = 0; ni < 4; ++ni) acc[mi][ni] = (f32x4){0.f, 0.f, 0.f, 0.f};

  for (int kt = 0; kt < K; kt += 64) {
    #pragma unroll
    for (int i = 0; i < 4; ++i) {
      int u = i * 256 + t;                 // 0..1023
      int row = u >> 3, c16 = u & 7;
      int sc = c16 ^ (row & 7);
      __builtin_amdgcn_global_load_lds(
          (const AS1 void*)(A + ((size_t)(m0 + row) * K + kt + sc * 8)),
          (AS3 void*)&As[(size_t)u * 8], 16, 0, 0);
      __builtin_amdgcn_global_load_lds(
          (const AS1 void*)(Bm + ((size_t)(n0 + row) * K + kt + sc * 8)),
          (AS3 void*)&Bs[(size_t)u * 8], 16, 0, 0);
    }
    __syncthreads();
    #pragma unroll
    for (int kks = 0; kks < 2; ++kks) {
      bf16x8 af[4], bfr[4];
      #pragma unroll
      for (int mi = 0; mi < 4; ++mi) {
        int r = wm * 64 + mi * 16 + lo;
        af[mi] = *(const bf16x8*)&As[r * 64 + (((kks * 4 + hi) ^ (r & 7)) * 8)];
      }
      #pragma unroll
      for (int ni = 0; ni < 4; ++ni) {
        int r = wn * 64 + ni * 16 + lo;
        bfr[ni] = *(const bf16x8*)&Bs[r * 64 + (((kks * 4 + hi) ^ (r & 7)) * 8)];
      }
      #pragma unroll
      for (int mi = 0; mi < 4; ++mi)
        #pragma unroll
        for (int ni = 0; ni < 4; ++ni)
          acc[mi][ni] = __builtin_amdgcn_mfma_f32_16x16x32_bf16(af[mi], bfr[ni], acc[mi][ni], 0, 0, 0);
    }
    __syncthreads();
  }

  // epilogue. D layout: col = lane&15, row = (lane>>4)*4 + j  [m89-verified]
  if (EPI == 1) {
    #pragma unroll
    for (int mi = 0; mi < 4; ++mi) {
      int rbase = m0 + wm * 64 + mi * 16 + hi * 4;
      #pragma unroll
      for (int ni = 0; ni < 4; ++ni) {
        int c = n0 + wn * 64 + ni * 16 + lo;
        f32x4 v = acc[mi][ni];
        #pragma unroll
        for (int j = 0; j < 4; ++j)
          fo[(size_t)(rbase + j) * N + c] = v[j];
      }
    }
    return;
  }
  // EPI == 0: block-uniform section
  int sec = n0 / 768;
  if (sec < 2) {
    #pragma unroll
    for (int mi = 0; mi < 4; ++mi) {
      int rbase = m0 + wm * 64 + mi * 16 + hi * 4;
      #pragma unroll
      for (int ni = 0; ni < 4; ++ni) {
        int cc = n0 - sec * 768 + wn * 64 + ni * 16 + lo;
        int hh = cc >> 7, dd = cc & 127;
        f32x4 v = acc[mi][ni];
        #pragma unroll
        for (int j = 0; j < 4; ++j) {
          int r = rbase + j;
          int b = r >> 10, l = r & 1023;
          size_t bh = (size_t)(b * H_ + hh);
          if (sec == 0) qo[(bh * L_ + l) * D_ + dd] = f2bf(v[j] * 0.08838834764831845f);
          else          ko[(bh * L_ + l) * D_ + dd] = f2bf(v[j]);
        }
      }
    }
    return;
  }
  // sec == 2: V third. h is block-uniform.
  int hh = (n0 - 1536) >> 7;
  int b = m0 >> 10, l0 = m0 & 1023;
  size_t bh = (size_t)(b * H_ + hh);
  if (hh == 0) {
    // eye head: only row-major v needed
    #pragma unroll
    for (int mi = 0; mi < 4; ++mi) {
      int lb = wm * 64 + mi * 16 + hi * 4;
      #pragma unroll
      for (int ni = 0; ni < 4; ++ni) {
        int dd = wn * 64 + ni * 16 + lo;
        f32x4 v = acc[mi][ni];
        #pragma unroll
        for (int j = 0; j < 4; ++j)
          vo[(bh * L_ + l0 + lb + j) * D_ + dd] = f2bf(v[j]);
      }
    }
    return;
  }
  // h != 0: only vT needed. LDS transpose, XOR (dd&7)<<4 both sides.
  #pragma unroll
  for (int mi = 0; mi < 4; ++mi) {
    int lb = wm * 64 + mi * 16 + hi * 4;
    #pragma unroll
    for (int ni = 0; ni < 4; ++ni) {
      int dd = wn * 64 + ni * 16 + lo;
      ushort_t* base = (dd < 64) ? As : Bs;
      f32x4 v = acc[mi][ni];
      #pragma unroll
      for (int j = 0; j < 4; ++j) {
        int byte = (((dd & 63) * 256 + (lb + j) * 2)) ^ ((dd & 7) << 4);
        *(ushort_t*)((char*)base + byte) = f2bf(v[j]);
      }
    }
  }
  __syncthreads();
  #pragma unroll
  for (int i = 0; i < 8; ++i) {
    int u = i * 256 + t;            // 2048 chunks: dd 0..127 x 16 16B-chunks
    int ddl = u >> 4, c16 = u & 15;
    const ushort_t* base = (ddl < 64) ? As : Bs;
    int byte = (((ddl & 63) * 256 + c16 * 16)) ^ ((ddl & 7) << 4);
    bf16x8 val = *(const bf16x8*)((const char*)base + byte);
    *(bf16x8*)(vTo + (bh * D_ + ddl) * L_ + l0 + c16 * 8) = val;
  }
}

// ------------------------------------------------- flash attention, split-K=4
// 8 waves / block, 256 q-rows (32/wave); kv quarter per blockIdx.z.
// KVBLK=64: 4 chunks/block (half R13's barrier count at the same staged
// bytes); two 32-k subtiles per chunk (R8-verified inner loop).
__global__ __launch_bounds__(512)
void attn_kernel(const ushort_t* __restrict__ q, const ushort_t* __restrict__ k,
                 const ushort_t* __restrict__ vT, const ushort_t* __restrict__ v,
                 ushort_t* __restrict__ obf,
                 ushort_t* __restrict__ np0, ushort_t* __restrict__ np1,
                 ushort_t* __restrict__ np2, ushort_t* __restrict__ np3,
                 float* __restrict__ ml,
                 const u64* __restrict__ a1p, const u64* __restrict__ a2p,
                 const u64* __restrict__ d2p, const u64* __restrict__ d3p) {
  __shared__ __align__(16) ushort_t Ks[2][64 * 128];   // [krow][d]  16 KB x2
  __shared__ __align__(16) ushort_t Vs[2][128 * 64];   // [d][kcol]  16 KB x2
  int t = threadIdx.x;
  int lane = t & 63, lo32 = lane & 31, hi2 = (lane >> 5) & 1, wv = t >> 6;
  int bh = blockIdx.x, qt = blockIdx.y, quar = blockIdx.z;
  int b = bh / H_, h = bh - b * H_;
  int qbase = qt * 256;
  int qw = qbase + wv * 32;
  int kvb = quar * 256;

  if (h == 0) {
    if (quar) return;
    // eye mask: out = v[l]  (h*D_ == 0 in output)
    const ushort_t* vp0 = v + ((size_t)bh * L_ + qbase) * D_;
    ushort_t* op0 = obf + ((size_t)b * L_ + qbase) * C_;
    #pragma unroll
    for (int it = 0; it < 8; ++it) {
      int u = it * 512 + t;
      int r = u >> 4, c = (u & 15) * 8;
      *(bf16x8*)(op0 + (size_t)r * C_ + c) = *(const bf16x8*)(vp0 + (size_t)r * D_ + c);
    }
    return;
  }

  const ushort_t* qp = q + (size_t)bh * L_ * D_;
  const ushort_t* kp = k + (size_t)bh * L_ * D_ + (size_t)kvb * D_;
  const ushort_t* vp = vT + (size_t)bh * D_ * L_ + kvb;

  bf16x8 qf[8];
  #pragma unroll
  for (int dt = 0; dt < 8; ++dt)
    qf[dt] = *(const bf16x8*)(qp + (size_t)(qw + lo32) * D_ + dt * 16 + hi2 * 8);

  const u64* mp = (h == 1) ? a1p : (h == 2) ? a2p : (h == 3) ? d2p : d3p;
  bool full = (h == 5);
  const u64* mrow = mp + ((size_t)b * L_ + qw + lo32) * 16 + quar * 4;

  float m_run = NEGINF, l_run = 0.f;
  f32x16 acc[4];
  #pragma unroll
  for (int dt = 0; dt < 4; ++dt)
    #pragma unroll
    for (int r = 0; r < 16; ++r) acc[dt][r] = 0.f;

  // stage one 64-col K/V chunk: 4 global_load_lds per thread (512 threads)
  auto stage = [&](int buf, int ch) {
    int kc0 = ch * 64;
    #pragma unroll
    for (int i = 0; i < 2; ++i) {
      int u = i * 512 + t;                 // K: 64 rows x 16 slots (1024 chunks)
      int row = u >> 4, c16 = u & 15;
      int sc = c16 ^ (row & 15);
      __builtin_amdgcn_global_load_lds(
          (const AS1 void*)(kp + (size_t)(kc0 + row) * D_ + sc * 8),
          (AS3 void*)&Ks[buf][(size_t)u * 8], 16, 0, 0);
    }
    #pragma unroll
    for (int i = 0; i < 2; ++i) {
      int u = i * 512 + t;                 // V: 128 rows x 8 slots (1024 chunks)
      int row = u >> 3, c16 = u & 7;
      int sc = c16 ^ (row & 7);
      __builtin_amdgcn_global_load_lds(
          (const AS1 void*)(vp + (size_t)row * L_ + kc0 + sc * 8),
          (AS3 void*)&Vs[buf][(size_t)u * 8], 16, 0, 0);
    }
  };

  stage(0, 0);
  u64 mw_cur = full ? 0ULL : mrow[0];
  u64 mw_nxt = 0ULL;
  __syncthreads();

  for (int ch = 0; ch < 4; ++ch) {
    int cur = ch & 1;
    if (ch < 3) { stage(cur ^ 1, ch + 1); if (!full) mw_nxt = mrow[ch + 1]; }

    const ushort_t* ks = &Ks[cur][0];
    const ushort_t* vs = &Vs[cur][0];

    #pragma unroll
    for (int s = 0; s < 2; ++s) {                   // two 32-k subtiles
      // S^T subtile: sacc[r] = S[q=lo32][kvb + 64ch + 32s + crow(r,hi2)]
      f32x16 sacc;
      #pragma unroll
      for (int r = 0; r < 16; ++r) sacc[r] = 0.f;
      __builtin_amdgcn_s_setprio(1);
      #pragma unroll
      for (int dt = 0; dt < 8; ++dt) {
        int krow = s * 32 + lo32;
        int c16 = (dt * 2 + hi2) ^ (krow & 15);
        bf16x8 kf = *(const bf16x8*)&ks[krow * 128 + c16 * 8];
        sacc = __builtin_amdgcn_mfma_f32_32x32x16_bf16(kf, qf[dt], sacc, 0, 0, 0);
      }
      __builtin_amdgcn_s_setprio(0);

      uint_t mbits = full ? 0xffffffffu : (uint_t)(mw_cur >> (32 * s));
      float sv[16];
      #pragma unroll
      for (int r = 0; r < 16; ++r) {
        int shift = (r & 3) + 8 * (r >> 2) + hi2 * 4;
        sv[r] = ((mbits >> shift) & 1u) ? sacc[r] : NEGINF;
      }

      // in-lane max tree + 1 cross-lane
      float a8[8];
      #pragma unroll
      for (int j = 0; j < 8; ++j) a8[j] = fmaxf(sv[2 * j], sv[2 * j + 1]);
      #pragma unroll
      for (int j = 0; j < 4; ++j) a8[j] = fmaxf(a8[j], a8[j + 4]);
      float pmax = fmaxf(fmaxf(a8[0], a8[1]), fmaxf(a8[2], a8[3]));
      pmax = fmaxf(pmax, __shfl_xor(pmax, 32));

      // defer-max (T13)
      if (__any(pmax > m_run + THR_)) {
        float mn = fmaxf(m_run, pmax);
        float corr = __expf(m_run - mn);
        l_run *= corr;
        m_run = mn;
        float cT[16];
        #pragma unroll
        for (int r = 0; r < 16; ++r)
          cT[r] = __shfl(corr, (r & 3) + 8 * (r >> 2) + hi2 * 4);
        #pragma unroll
        for (int dt = 0; dt < 4; ++dt)
          #pragma unroll
          for (int r = 0; r < 16; ++r) acc[dt][r] *= cT[r];
      }

      // P = exp(S - m_run); row-sum
      float p[16];
      #pragma unroll
      for (int r = 0; r < 16; ++r) p[r] = __expf(sv[r] - m_run);
      float s8[8];
      #pragma unroll
      for (int j = 0; j < 8; ++j) s8[j] = p[2 * j] + p[2 * j + 1];
      #pragma unroll
      for (int j = 0; j < 4; ++j) s8[j] = s8[j] + s8[j + 4];
      float rs = (s8[0] + s8[1]) + (s8[2] + s8[3]);
      rs += __shfl_xor(rs, 32);
      l_run += rs;

      // pack P; half-swap to build PV A-frags (R6/R8-verified)
      uint_t ow[8];
      #pragma unroll
      for (int j = 0; j < 8; ++j)
        ow[j] = (uint_t)f2bf(p[2 * j]) | ((uint_t)f2bf(p[2 * j + 1]) << 16);
      uint_t pw[8];
      #pragma unroll
      for (int j = 0; j < 8; ++j) pw[j] = __shfl_xor(ow[j], 32);
      u32x4 pa0 = (u32x4){hi2 ? pw[2] : ow[0], hi2 ? pw[3] : ow[1],
                          hi2 ? ow[2] : pw[0], hi2 ? ow[3] : pw[1]};
      u32x4 pa1 = (u32x4){hi2 ? pw[6] : ow[4], hi2 ? pw[7] : ow[5],
                          hi2 ? ow[6] : pw[4], hi2 ? ow[7] : pw[5]};
      bf16x8 paf0 = __builtin_bit_cast(bf16x8, pa0);
      bf16x8 paf1 = __builtin_bit_cast(bf16x8, pa1);

      // PV: B-frags from swizzled Vs (R8-verified slot math)
      __builtin_amdgcn_s_setprio(1);
      #pragma unroll
      for (int dt = 0; dt < 4; ++dt) {
        int vd = dt * 32 + lo32;
        int c16a = (s * 4 + hi2) ^ (vd & 7);
        int c16b = (s * 4 + 2 + hi2) ^ (vd & 7);
        bf16x8 vfa = *(const bf16x8*)&vs[vd * 64 + c16a * 8];
        bf16x8 vfb = *(const bf16x8*)&vs[vd * 64 + c16b * 8];
        acc[dt] = __builtin_amdgcn_mfma_f32_32x32x16_bf16(paf0, vfa, acc[dt], 0, 0, 0);
        acc[dt] = __builtin_amdgcn_mfma_f32_32x32x16_bf16(paf1, vfb, acc[dt], 0, 0, 0);
      }
      __builtin_amdgcn_s_setprio(0);
    }
    mw_cur = mw_nxt;
    __syncthreads();
  }

  // epilogue: write partials. (m,l) per q-row (hi2==0 lanes); N unnormalized bf16.
  if (hi2 == 0) {
    size_t row = (size_t)bh * L_ + qw + lo32;
    float2 v2 = make_float2(m_run, l_run);
    *(float2*)(ml + ((size_t)quar * BH_ * L_ + row) * 2) = v2;
  }
  ushort_t* np = (quar == 0) ? np0 : (quar == 1) ? np1 : (quar == 2) ? np2 : np3;
  #pragma unroll
  for (int dt = 0; dt < 4; ++dt)
    #pragma unroll
    for (int r = 0; r < 16; ++r) {
      int qrow = qw + (r & 3) + 8 * (r >> 2) + hi2 * 4;
      np[((size_t)bh * L_ + qrow) * D_ + dt * 32 + lo32] = f2bf(acc[dt][r]);
    }
}

// ------------------------------------------------- split-K combine (4-way)
__global__ __launch_bounds__(256)
void combine(const ushort_t* __restrict__ np0, const ushort_t* __restrict__ np1,
             const ushort_t* __restrict__ np2, const ushort_t* __restrict__ np3,
             const float* __restrict__ ml, ushort_t* __restrict__ obf) {
  int bh = blockIdx.x;
  int b = bh / H_, h = bh - b * H_;
  if (h == 0) return;                       // eye head written directly
  int t = threadIdx.x;
  int qi = t >> 4, di = t & 15;             // 16 q-rows x 16 d-groups of 8
  int qq = blockIdx.y * 16 + qi;
  size_t row = (size_t)bh * L_ + qq;
  float2 mlv[4];
  #pragma unroll
  for (int s = 0; s < 4; ++s)
    mlv[s] = *(const float2*)(ml + ((size_t)s * BH_ * L_ + row) * 2);
  float M = fmaxf(fmaxf(mlv[0].x, mlv[1].x), fmaxf(mlv[2].x, mlv[3].x));
  float w[4], lsum = 0.f;
  #pragma unroll
  for (int s = 0; s < 4; ++s) { w[s] = __expf(mlv[s].x - M); lsum += w[s] * mlv[s].y; }
  float inv = 1.f / lsum;
  bf16x8 n0 = *(const bf16x8*)(np0 + row * D_ + di * 8);
  bf16x8 n1 = *(const bf16x8*)(np1 + row * D_ + di * 8);
  bf16x8 n2 = *(const bf16x8*)(np2 + row * D_ + di * 8);
  bf16x8 n3 = *(const bf16x8*)(np3 + row * D_ + di * 8);
  ushort_t o[8];
  #pragma unroll
  for (int j = 0; j < 8; ++j)
    o[j] = f2bf((w[0] * bf2f((ushort_t)n0[j]) + w[1] * bf2f((ushort_t)n1[j]) +
                 w[2] * bf2f((ushort_t)n2[j]) + w[3] * bf2f((ushort_t)n3[j])) * inv);
  *(bf16x8*)(obf + ((size_t)b * L_ + qq) * C_ + h * D_ + di * 8) = *(bf16x8*)o;
}

// ---------------------------------------------------------------- launcher
extern "C" void kernel_launch(void* const* d_in, const int* in_sizes, int n_in,
                              void* d_out, int out_size, void* d_ws, size_t ws_size,
                              hipStream_t stream) {
  const float* x     = (const float*)d_in[0];
  const int*   adj   = (const int*)d_in[1];
  const int*   dist  = (const int*)d_in[2];
  const float* wqkv  = (const float*)d_in[3];
  const float* wproj = (const float*)d_in[4];
  float* out = (float*)d_out;
  char* ws = (char*)d_ws;

  const size_t SZ_X   = (size_t)B_ * L_ * C_ * 2;        // 12.6 MB (== SZ_QKV)
  const size_t SZ_WQ  = (size_t)3 * C_ * C_ * 2;
  const size_t SZ_WP  = (size_t)C_ * C_ * 2;
  const size_t SZ_QKV = (size_t)BH_ * L_ * D_ * 2;       // 12.6 MB
  const size_t SZ_MSK = (size_t)B_ * L_ * 16 * 8;        // 1 MB
  const size_t SZ_ML  = (size_t)4 * BH_ * L_ * 2 * 4;    // 1.6 MB
  size_t off = 0;
  ushort_t* xbf  = (ushort_t*)(ws + off); off += SZ_X;   // reused as np0 post-GEMM
  ushort_t* wqb  = (ushort_t*)(ws + off); off += SZ_WQ;
  ushort_t* wpb  = (ushort_t*)(ws + off); off += SZ_WP;
  ushort_t* qb   = (ushort_t*)(ws + off); off += SZ_QKV;
  ushort_t* kb   = (ushort_t*)(ws + off); off += SZ_QKV;
  ushort_t* vTb  = (ushort_t*)(ws + off); off += SZ_QKV;
  ushort_t* vb   = (ushort_t*)(ws + off); off += SZ_QKV;
  ushort_t* ob   = (ushort_t*)(ws + off); off += SZ_X;
  u64* a1p = (u64*)(ws + off); off += SZ_MSK;
  u64* a2p = (u64*)(ws + off); off += SZ_MSK;
  u64* d2p = (u64*)(ws + off); off += SZ_MSK;
  u64* d3p = (u64*)(ws + off); off += SZ_MSK;
  ushort_t* np1 = (ushort_t*)(ws + off); off += SZ_QKV;  // partial N quarter 1
  ushort_t* np2 = (ushort_t*)(ws + off); off += SZ_QKV;  // partial N quarter 2
  ushort_t* np3 = (ushort_t*)(ws + off); off += SZ_QKV;  // partial N quarter 3
  float*    mlb = (float*)(ws + off); off += SZ_ML;      // (m,l)[4][BH][L]
  ushort_t* np0 = xbf;                                   // partial N quarter 0
  (void)ws_size; (void)n_in; (void)in_sizes; (void)out_size;

  cvt_f32_bf16<<<(B_ * L_ * C_ / 8 + 255) / 256, 256, 0, stream>>>(x, xbf, B_ * L_ * C_ / 8);
  cvt_f32_bf16<<<(3 * C_ * C_ / 8 + 255) / 256, 256, 0, stream>>>(wqkv, wqb, 3 * C_ * C_ / 8);
  cvt_f32_bf16<<<(C_ * C_ / 8 + 255) / 256, 256, 0, stream>>>(wproj, wpb, C_ * C_ / 8);
  pack_masks<<<dim3(L_, B_), 256, 0, stream>>>(adj, dist, a1p, d2p, d3p);
  hop2<<<B_ * L_ / 64, 64, 0, stream>>>(a1p, a2p);
  // qkv = x @ wqkv^T  (M=8192, N=2304, K=768), nwg=1152 (%8==0)
  gemm_bt<0><<<dim3(3 * C_ / 128, B_ * L_ / 128), 256, 0, stream>>>(
      xbf, wqb, 3 * C_, C_, qb, kb, vTb, vb, nullptr);
  // attention split-K=4: 8-wave blocks, 256 q-rows, KVBLK=64 (4 chunks)
  attn_kernel<<<dim3(BH_, L_ / 256, 4), 512, 0, stream>>>(
      qb, kb, vTb, vb, ob, np0, np1, np2, np3, mlb, a1p, a2p, d2p, d3p);
  combine<<<dim3(BH_, L_ / 16), 256, 0, stream>>>(np0, np1, np2, np3, mlb, ob);
  // out = O @ wproj^T  (M=8192, N=768, K=768), nwg=384 (%8==0)
  gemm_bt<1><<<dim3(C_ / 128, B_ * L_ / 128), 256, 0, stream>>>(
      ob, wpb, C_, C_, nullptr, nullptr, nullptr, nullptr, out);
}

// Round 19
// 173.683 us; speedup vs baseline: 1.1607x; 1.0083x over previous
//
#include <hip/hip_runtime.h>

typedef unsigned short ushort_t;
typedef unsigned int uint_t;
typedef unsigned long long u64;
typedef __attribute__((ext_vector_type(8))) short bf16x8;
typedef __attribute__((ext_vector_type(4))) float f32x4;
typedef __attribute__((ext_vector_type(16))) float f32x16;
typedef __attribute__((ext_vector_type(4))) uint_t u32x4;

#define B_ 8
#define L_ 1024
#define C_ 768
#define H_ 6
#define D_ 128
#define BH_ 48
#define NEGINF (-1e9f)
#define THR_ 8.0f

#define AS1 __attribute__((address_space(1)))
#define AS3 __attribute__((address_space(3)))

// round-to-nearest-even f32 -> bf16
__device__ __forceinline__ ushort_t f2bf(float f) {
  uint_t u = __builtin_bit_cast(uint_t, f);
  u += 0x7fffu + ((u >> 16) & 1u);
  return (ushort_t)(u >> 16);
}
__device__ __forceinline__ float bf2f(ushort_t s) {
  uint_t u = ((uint_t)s) << 16;
  return __builtin_bit_cast(float, u);
}

// ---------------------------------------------------------------- converts
__global__ void cvt_f32_bf16(const float* __restrict__ in, ushort_t* __restrict__ out, int n8) {
  int i = blockIdx.x * 256 + threadIdx.x;
  if (i >= n8) return;
  const float4* p = (const float4*)in + (size_t)i * 2;
  float4 a = p[0], b = p[1];
  uint4 r;
  r.x = (uint_t)f2bf(a.x) | ((uint_t)f2bf(a.y) << 16);
  r.y = (uint_t)f2bf(a.z) | ((uint_t)f2bf(a.w) << 16);
  r.z = (uint_t)f2bf(b.x) | ((uint_t)f2bf(b.y) << 16);
  r.w = (uint_t)f2bf(b.z) | ((uint_t)f2bf(b.w) << 16);
  ((uint4*)out)[i] = r;
}

// ------------------------------------------------- bit-pack a1 / d<=2 / d<=3
__global__ __launch_bounds__(256)
void pack_masks(const int* __restrict__ adj, const int* __restrict__ dist,
                u64* __restrict__ a1p, u64* __restrict__ d2p, u64* __restrict__ d3p) {
  int l = blockIdx.x, b = blockIdx.y, t = threadIdx.x;
  size_t base = ((size_t)b * L_ + l) * L_;
  size_t rb = ((size_t)b * L_ + l) * 16;
  #pragma unroll
  for (int it = 0; it < 4; ++it) {
    int c = it * 256 + t;
    int av = adj[base + c];
    int dv = dist[base + c];
    u64 m1 = __ballot((av > 0) || (c == l));
    u64 m2 = __ballot(dv <= 2);
    u64 m3 = __ballot(dv <= 3);
    if ((t & 63) == 0) {
      int w = it * 4 + (t >> 6);
      a1p[rb + w] = m1; d2p[rb + w] = m2; d3p[rb + w] = m3;
    }
  }
}

// ------------------------------------------------- 2-hop closure (bit OR)
__global__ __launch_bounds__(64)
void hop2(const u64* __restrict__ a1p, u64* __restrict__ a2p) {
  int tid = blockIdx.x * 64 + threadIdx.x;   // 0..8191 = (b,l)
  int b = tid >> 10;
  size_t rb = (size_t)tid * 16;
  u64 row[16], acc[16];
  #pragma unroll
  for (int j = 0; j < 16; ++j) { row[j] = a1p[rb + j]; acc[j] = 0ULL; }
  bool done = false;
  #pragma unroll
  for (int mw = 0; mw < 16; ++mw) {
    if (done) continue;
    u64 bits = row[mw];
    while (bits) {
      int tz = __builtin_ctzll(bits); bits &= bits - 1;
      const u64* src = a1p + (((size_t)b << 10) + (mw << 6) + tz) * 16;
      u64 band = ~0ULL;
      #pragma unroll
      for (int j = 0; j < 16; ++j) { acc[j] |= src[j]; band &= acc[j]; }
      if (band == ~0ULL) { done = true; break; }
    }
  }
  #pragma unroll
  for (int j = 0; j < 16; ++j) a2p[rb + j] = acc[j];
}

// ------------------------------------------------- bf16 GEMM  C = A @ B^T
// 128x128 tile, BK=64, T2 both-sides XOR swizzle, bijective XCD swizzle.
// EPI==0 epilogue is BLOCK-UNIFORM in sec (n-tiles 128-wide, 768%128==0):
//   sec0 -> q (scaled), sec1 -> k, sec2 h==0 -> eye-head output DIRECTLY
//   into ob (out = v for the eye mask; h*D==0), sec2 h!=0 -> vT via LDS
//   transpose. No separate row-major v buffer round-trip.
template<int EPI>
__global__ __launch_bounds__(256)
void gemm_bt(const ushort_t* __restrict__ A, const ushort_t* __restrict__ Bm,
             int N, int K,
             ushort_t* __restrict__ qo, ushort_t* __restrict__ ko,
             ushort_t* __restrict__ vTo, ushort_t* __restrict__ obf,
             float* __restrict__ fo) {
  __shared__ __align__(16) ushort_t As[128 * 64];   // 16 KB
  __shared__ __align__(16) ushort_t Bs[128 * 64];   // 16 KB
  int t = threadIdx.x;
  int lane = t & 63, lo = lane & 15, hi = lane >> 4;
  int wv = t >> 6, wm = wv >> 1, wn = wv & 1;

  int gx = gridDim.x;
  int nwg = gx * gridDim.y;
  int orig = blockIdx.y * gx + blockIdx.x;
  int cpx = nwg >> 3;
  int wg = (orig & 7) * cpx + (orig >> 3);
  int n0 = (wg % gx) * 128;
  int m0 = (wg / gx) * 128;

  f32x4 acc[4][4];
  #pragma unroll
  for (int mi = 0; mi < 4; ++mi)
    #pragma unroll
    for (int ni = 0; ni < 4; ++ni) acc[mi][ni] = (f32x4){0.f, 0.f, 0.f, 0.f};

  for (int kt = 0; kt < K; kt += 64) {
    #pragma unroll
    for (int i = 0; i < 4; ++i) {
      int u = i * 256 + t;                 // 0..1023
      int row = u >> 3, c16 = u & 7;
      int sc = c16 ^ (row & 7);
      __builtin_amdgcn_global_load_lds(
          (const AS1 void*)(A + ((size_t)(m0 + row) * K + kt + sc * 8)),
          (AS3 void*)&As[(size_t)u * 8], 16, 0, 0);
      __builtin_amdgcn_global_load_lds(
          (const AS1 void*)(Bm + ((size_t)(n0 + row) * K + kt + sc * 8)),
          (AS3 void*)&Bs[(size_t)u * 8], 16, 0, 0);
    }
    __syncthreads();
    #pragma unroll
    for (int kks = 0; kks < 2; ++kks) {
      bf16x8 af[4], bfr[4];
      #pragma unroll
      for (int mi = 0; mi < 4; ++mi) {
        int r = wm * 64 + mi * 16 + lo;
        af[mi] = *(const bf16x8*)&As[r * 64 + (((kks * 4 + hi) ^ (r & 7)) * 8)];
      }
      #pragma unroll
      for (int ni = 0; ni < 4; ++ni) {
        int r = wn * 64 + ni * 16 + lo;
        bfr[ni] = *(const bf16x8*)&Bs[r * 64 + (((kks * 4 + hi) ^ (r & 7)) * 8)];
      }
      #pragma unroll
      for (int mi = 0; mi < 4; ++mi)
        #pragma unroll
        for (int ni = 0; ni < 4; ++ni)
          acc[mi][ni] = __builtin_amdgcn_mfma_f32_16x16x32_bf16(af[mi], bfr[ni], acc[mi][ni], 0, 0, 0);
    }
    __syncthreads();
  }

  // epilogue. D layout: col = lane&15, row = (lane>>4)*4 + j  [m89-verified]
  if (EPI == 1) {
    #pragma unroll
    for (int mi = 0; mi < 4; ++mi) {
      int rbase = m0 + wm * 64 + mi * 16 + hi * 4;
      #pragma unroll
      for (int ni = 0; ni < 4; ++ni) {
        int c = n0 + wn * 64 + ni * 16 + lo;
        f32x4 v = acc[mi][ni];
        #pragma unroll
        for (int j = 0; j < 4; ++j)
          fo[(size_t)(rbase + j) * N + c] = v[j];
      }
    }
    return;
  }
  // EPI == 0: block-uniform section
  int sec = n0 / 768;
  if (sec < 2) {
    #pragma unroll
    for (int mi = 0; mi < 4; ++mi) {
      int rbase = m0 + wm * 64 + mi * 16 + hi * 4;
      #pragma unroll
      for (int ni = 0; ni < 4; ++ni) {
        int cc = n0 - sec * 768 + wn * 64 + ni * 16 + lo;
        int hh = cc >> 7, dd = cc & 127;
        f32x4 v = acc[mi][ni];
        #pragma unroll
        for (int j = 0; j < 4; ++j) {
          int r = rbase + j;
          int b = r >> 10, l = r & 1023;
          size_t bh = (size_t)(b * H_ + hh);
          if (sec == 0) qo[(bh * L_ + l) * D_ + dd] = f2bf(v[j] * 0.08838834764831845f);
          else          ko[(bh * L_ + l) * D_ + dd] = f2bf(v[j]);
        }
      }
    }
    return;
  }
  // sec == 2: V third. h is block-uniform.
  int hh = (n0 - 1536) >> 7;
  int b = m0 >> 10, l0 = m0 & 1023;
  size_t bh = (size_t)(b * H_ + hh);
  if (hh == 0) {
    // eye head: softmax over diagonal element == v -> write final output
    // directly (h*D_ == 0 column offset in ob)
    #pragma unroll
    for (int mi = 0; mi < 4; ++mi) {
      int lb = wm * 64 + mi * 16 + hi * 4;
      #pragma unroll
      for (int ni = 0; ni < 4; ++ni) {
        int dd = wn * 64 + ni * 16 + lo;
        f32x4 v = acc[mi][ni];
        #pragma unroll
        for (int j = 0; j < 4; ++j)
          obf[((size_t)b * L_ + l0 + lb + j) * C_ + dd] = f2bf(v[j]);
      }
    }
    return;
  }
  // h != 0: only vT needed. LDS transpose, XOR (dd&7)<<4 both sides.
  #pragma unroll
  for (int mi = 0; mi < 4; ++mi) {
    int lb = wm * 64 + mi * 16 + hi * 4;
    #pragma unroll
    for (int ni = 0; ni < 4; ++ni) {
      int dd = wn * 64 + ni * 16 + lo;
      ushort_t* base = (dd < 64) ? As : Bs;
      f32x4 v = acc[mi][ni];
      #pragma unroll
      for (int j = 0; j < 4; ++j) {
        int byte = (((dd & 63) * 256 + (lb + j) * 2)) ^ ((dd & 7) << 4);
        *(ushort_t*)((char*)base + byte) = f2bf(v[j]);
      }
    }
  }
  __syncthreads();
  #pragma unroll
  for (int i = 0; i < 8; ++i) {
    int u = i * 256 + t;            // 2048 chunks: dd 0..127 x 16 16B-chunks
    int ddl = u >> 4, c16 = u & 15;
    const ushort_t* base = (ddl < 64) ? As : Bs;
    int byte = (((ddl & 63) * 256 + c16 * 16)) ^ ((ddl & 7) << 4);
    bf16x8 val = *(const bf16x8*)((const char*)base + byte);
    *(bf16x8*)(vTo + (bh * D_ + ddl) * L_ + l0 + c16 * 8) = val;
  }
}

// ------------------------------------------------- flash attention, split-K=4
// 8 waves / block, 256 q-rows (32/wave); kv quarter per blockIdx.z.
// KVBLK=64: 4 chunks/block; two 32-k subtiles per chunk (R18-verified).
// Eye head (h==0) handled entirely by the qkv GEMM epilogue -> instant return.
__global__ __launch_bounds__(512)
void attn_kernel(const ushort_t* __restrict__ q, const ushort_t* __restrict__ k,
                 const ushort_t* __restrict__ vT,
                 ushort_t* __restrict__ np0, ushort_t* __restrict__ np1,
                 ushort_t* __restrict__ np2, ushort_t* __restrict__ np3,
                 float* __restrict__ ml,
                 const u64* __restrict__ a1p, const u64* __restrict__ a2p,
                 const u64* __restrict__ d2p, const u64* __restrict__ d3p) {
  __shared__ __align__(16) ushort_t Ks[2][64 * 128];   // [krow][d]  16 KB x2
  __shared__ __align__(16) ushort_t Vs[2][128 * 64];   // [d][kcol]  16 KB x2
  int t = threadIdx.x;
  int lane = t & 63, lo32 = lane & 31, hi2 = (lane >> 5) & 1, wv = t >> 6;
  int bh = blockIdx.x, qt = blockIdx.y, quar = blockIdx.z;
  int b = bh / H_, h = bh - b * H_;
  int qbase = qt * 256;
  int qw = qbase + wv * 32;
  int kvb = quar * 256;

  if (h == 0) return;   // eye head written directly by the qkv GEMM epilogue

  const ushort_t* qp = q + (size_t)bh * L_ * D_;
  const ushort_t* kp = k + (size_t)bh * L_ * D_ + (size_t)kvb * D_;
  const ushort_t* vp = vT + (size_t)bh * D_ * L_ + kvb;

  bf16x8 qf[8];
  #pragma unroll
  for (int dt = 0; dt < 8; ++dt)
    qf[dt] = *(const bf16x8*)(qp + (size_t)(qw + lo32) * D_ + dt * 16 + hi2 * 8);

  const u64* mp = (h == 1) ? a1p : (h == 2) ? a2p : (h == 3) ? d2p : d3p;
  bool full = (h == 5);
  const u64* mrow = mp + ((size_t)b * L_ + qw + lo32) * 16 + quar * 4;

  float m_run = NEGINF, l_run = 0.f;
  f32x16 acc[4];
  #pragma unroll
  for (int dt = 0; dt < 4; ++dt)
    #pragma unroll
    for (int r = 0; r < 16; ++r) acc[dt][r] = 0.f;

  // stage one 64-col K/V chunk: 4 global_load_lds per thread (512 threads)
  auto stage = [&](int buf, int ch) {
    int kc0 = ch * 64;
    #pragma unroll
    for (int i = 0; i < 2; ++i) {
      int u = i * 512 + t;                 // K: 64 rows x 16 slots (1024 chunks)
      int row = u >> 4, c16 = u & 15;
      int sc = c16 ^ (row & 15);
      __builtin_amdgcn_global_load_lds(
          (const AS1 void*)(kp + (size_t)(kc0 + row) * D_ + sc * 8),
          (AS3 void*)&Ks[buf][(size_t)u * 8], 16, 0, 0);
    }
    #pragma unroll
    for (int i = 0; i < 2; ++i) {
      int u = i * 512 + t;                 // V: 128 rows x 8 slots (1024 chunks)
      int row = u >> 3, c16 = u & 7;
      int sc = c16 ^ (row & 7);
      __builtin_amdgcn_global_load_lds(
          (const AS1 void*)(vp + (size_t)row * L_ + kc0 + sc * 8),
          (AS3 void*)&Vs[buf][(size_t)u * 8], 16, 0, 0);
    }
  };

  stage(0, 0);
  u64 mw_cur = full ? 0ULL : mrow[0];
  u64 mw_nxt = 0ULL;
  __syncthreads();

  for (int ch = 0; ch < 4; ++ch) {
    int cur = ch & 1;
    if (ch < 3) { stage(cur ^ 1, ch + 1); if (!full) mw_nxt = mrow[ch + 1]; }

    const ushort_t* ks = &Ks[cur][0];
    const ushort_t* vs = &Vs[cur][0];

    #pragma unroll
    for (int s = 0; s < 2; ++s) {                   // two 32-k subtiles
      // S^T subtile: sacc[r] = S[q=lo32][kvb + 64ch + 32s + crow(r,hi2)]
      f32x16 sacc;
      #pragma unroll
      for (int r = 0; r < 16; ++r) sacc[r] = 0.f;
      __builtin_amdgcn_s_setprio(1);
      #pragma unroll
      for (int dt = 0; dt < 8; ++dt) {
        int krow = s * 32 + lo32;
        int c16 = (dt * 2 + hi2) ^ (krow & 15);
        bf16x8 kf = *(const bf16x8*)&ks[krow * 128 + c16 * 8];
        sacc = __builtin_amdgcn_mfma_f32_32x32x16_bf16(kf, qf[dt], sacc, 0, 0, 0);
      }
      __builtin_amdgcn_s_setprio(0);

      uint_t mbits = full ? 0xffffffffu : (uint_t)(mw_cur >> (32 * s));
      float sv[16];
      #pragma unroll
      for (int r = 0; r < 16; ++r) {
        int shift = (r & 3) + 8 * (r >> 2) + hi2 * 4;
        sv[r] = ((mbits >> shift) & 1u) ? sacc[r] : NEGINF;
      }

      // in-lane max tree + 1 cross-lane
      float a8[8];
      #pragma unroll
      for (int j = 0; j < 8; ++j) a8[j] = fmaxf(sv[2 * j], sv[2 * j + 1]);
      #pragma unroll
      for (int j = 0; j < 4; ++j) a8[j] = fmaxf(a8[j], a8[j + 4]);
      float pmax = fmaxf(fmaxf(a8[0], a8[1]), fmaxf(a8[2], a8[3]));
      pmax = fmaxf(pmax, __shfl_xor(pmax, 32));

      // defer-max (T13)
      if (__any(pmax > m_run + THR_)) {
        float mn = fmaxf(m_run, pmax);
        float corr = __expf(m_run - mn);
        l_run *= corr;
        m_run = mn;
        float cT[16];
        #pragma unroll
        for (int r = 0; r < 16; ++r)
          cT[r] = __shfl(corr, (r & 3) + 8 * (r >> 2) + hi2 * 4);
        #pragma unroll
        for (int dt = 0; dt < 4; ++dt)
          #pragma unroll
          for (int r = 0; r < 16; ++r) acc[dt][r] *= cT[r];
      }

      // P = exp(S - m_run); row-sum
      float p[16];
      #pragma unroll
      for (int r = 0; r < 16; ++r) p[r] = __expf(sv[r] - m_run);
      float s8[8];
      #pragma unroll
      for (int j = 0; j < 8; ++j) s8[j] = p[2 * j] + p[2 * j + 1];
      #pragma unroll
      for (int j = 0; j < 4; ++j) s8[j] = s8[j] + s8[j + 4];
      float rs = (s8[0] + s8[1]) + (s8[2] + s8[3]);
      rs += __shfl_xor(rs, 32);
      l_run += rs;

      // pack P; half-swap to build PV A-frags (R6/R8-verified)
      uint_t ow[8];
      #pragma unroll
      for (int j = 0; j < 8; ++j)
        ow[j] = (uint_t)f2bf(p[2 * j]) | ((uint_t)f2bf(p[2 * j + 1]) << 16);
      uint_t pw[8];
      #pragma unroll
      for (int j = 0; j < 8; ++j) pw[j] = __shfl_xor(ow[j], 32);
      u32x4 pa0 = (u32x4){hi2 ? pw[2] : ow[0], hi2 ? pw[3] : ow[1],
                          hi2 ? ow[2] : pw[0], hi2 ? ow[3] : pw[1]};
      u32x4 pa1 = (u32x4){hi2 ? pw[6] : ow[4], hi2 ? pw[7] : ow[5],
                          hi2 ? ow[6] : pw[4], hi2 ? ow[7] : pw[5]};
      bf16x8 paf0 = __builtin_bit_cast(bf16x8, pa0);
      bf16x8 paf1 = __builtin_bit_cast(bf16x8, pa1);

      // PV: B-frags from swizzled Vs (R8-verified slot math)
      __builtin_amdgcn_s_setprio(1);
      #pragma unroll
      for (int dt = 0; dt < 4; ++dt) {
        int vd = dt * 32 + lo32;
        int c16a = (s * 4 + hi2) ^ (vd & 7);
        int c16b = (s * 4 + 2 + hi2) ^ (vd & 7);
        bf16x8 vfa = *(const bf16x8*)&vs[vd * 64 + c16a * 8];
        bf16x8 vfb = *(const bf16x8*)&vs[vd * 64 + c16b * 8];
        acc[dt] = __builtin_amdgcn_mfma_f32_32x32x16_bf16(paf0, vfa, acc[dt], 0, 0, 0);
        acc[dt] = __builtin_amdgcn_mfma_f32_32x32x16_bf16(paf1, vfb, acc[dt], 0, 0, 0);
      }
      __builtin_amdgcn_s_setprio(0);
    }
    mw_cur = mw_nxt;
    __syncthreads();
  }

  // epilogue: write partials. (m,l) per q-row (hi2==0 lanes); N unnormalized bf16.
  if (hi2 == 0) {
    size_t row = (size_t)bh * L_ + qw + lo32;
    float2 v2 = make_float2(m_run, l_run);
    *(float2*)(ml + ((size_t)quar * BH_ * L_ + row) * 2) = v2;
  }
  ushort_t* np = (quar == 0) ? np0 : (quar == 1) ? np1 : (quar == 2) ? np2 : np3;
  #pragma unroll
  for (int dt = 0; dt < 4; ++dt)
    #pragma unroll
    for (int r = 0; r < 16; ++r) {
      int qrow = qw + (r & 3) + 8 * (r >> 2) + hi2 * 4;
      np[((size_t)bh * L_ + qrow) * D_ + dt * 32 + lo32] = f2bf(acc[dt][r]);
    }
}

// ------------------------------------------------- split-K combine (4-way)
__global__ __launch_bounds__(256)
void combine(const ushort_t* __restrict__ np0, const ushort_t* __restrict__ np1,
             const ushort_t* __restrict__ np2, const ushort_t* __restrict__ np3,
             const float* __restrict__ ml, ushort_t* __restrict__ obf) {
  int bh = blockIdx.x;
  int b = bh / H_, h = bh - b * H_;
  if (h == 0) return;                       // eye head written by qkv GEMM
  int t = threadIdx.x;
  int qi = t >> 4, di = t & 15;             // 16 q-rows x 16 d-groups of 8
  int qq = blockIdx.y * 16 + qi;
  size_t row = (size_t)bh * L_ + qq;
  float2 mlv[4];
  #pragma unroll
  for (int s = 0; s < 4; ++s)
    mlv[s] = *(const float2*)(ml + ((size_t)s * BH_ * L_ + row) * 2);
  float M = fmaxf(fmaxf(mlv[0].x, mlv[1].x), fmaxf(mlv[2].x, mlv[3].x));
  float w[4], lsum = 0.f;
  #pragma unroll
  for (int s = 0; s < 4; ++s) { w[s] = __expf(mlv[s].x - M); lsum += w[s] * mlv[s].y; }
  float inv = 1.f / lsum;
  bf16x8 n0 = *(const bf16x8*)(np0 + row * D_ + di * 8);
  bf16x8 n1 = *(const bf16x8*)(np1 + row * D_ + di * 8);
  bf16x8 n2 = *(const bf16x8*)(np2 + row * D_ + di * 8);
  bf16x8 n3 = *(const bf16x8*)(np3 + row * D_ + di * 8);
  ushort_t o[8];
  #pragma unroll
  for (int j = 0; j < 8; ++j)
    o[j] = f2bf((w[0] * bf2f((ushort_t)n0[j]) + w[1] * bf2f((ushort_t)n1[j]) +
                 w[2] * bf2f((ushort_t)n2[j]) + w[3] * bf2f((ushort_t)n3[j])) * inv);
  *(bf16x8*)(obf + ((size_t)b * L_ + qq) * C_ + h * D_ + di * 8) = *(bf16x8*)o;
}

// ---------------------------------------------------------------- launcher
extern "C" void kernel_launch(void* const* d_in, const int* in_sizes, int n_in,
                              void* d_out, int out_size, void* d_ws, size_t ws_size,
                              hipStream_t stream) {
  const float* x     = (const float*)d_in[0];
  const int*   adj   = (const int*)d_in[1];
  const int*   dist  = (const int*)d_in[2];
  const float* wqkv  = (const float*)d_in[3];
  const float* wproj = (const float*)d_in[4];
  float* out = (float*)d_out;
  char* ws = (char*)d_ws;

  const size_t SZ_X   = (size_t)B_ * L_ * C_ * 2;        // 12.6 MB (== SZ_QKV)
  const size_t SZ_WQ  = (size_t)3 * C_ * C_ * 2;
  const size_t SZ_WP  = (size_t)C_ * C_ * 2;
  const size_t SZ_QKV = (size_t)BH_ * L_ * D_ * 2;       // 12.6 MB
  const size_t SZ_MSK = (size_t)B_ * L_ * 16 * 8;        // 1 MB
  const size_t SZ_ML  = (size_t)4 * BH_ * L_ * 2 * 4;    // 1.6 MB
  size_t off = 0;
  ushort_t* xbf  = (ushort_t*)(ws + off); off += SZ_X;   // reused as np0 post-GEMM
  ushort_t* wqb  = (ushort_t*)(ws + off); off += SZ_WQ;
  ushort_t* wpb  = (ushort_t*)(ws + off); off += SZ_WP;
  ushort_t* qb   = (ushort_t*)(ws + off); off += SZ_QKV;
  ushort_t* kb   = (ushort_t*)(ws + off); off += SZ_QKV;
  ushort_t* vTb  = (ushort_t*)(ws + off); off += SZ_QKV;
  ushort_t* vb   = (ushort_t*)(ws + off); off += SZ_QKV; (void)vb; // unused (kept for layout)
  ushort_t* ob   = (ushort_t*)(ws + off); off += SZ_X;
  u64* a1p = (u64*)(ws + off); off += SZ_MSK;
  u64* a2p = (u64*)(ws + off); off += SZ_MSK;
  u64* d2p = (u64*)(ws + off); off += SZ_MSK;
  u64* d3p = (u64*)(ws + off); off += SZ_MSK;
  ushort_t* np1 = (ushort_t*)(ws + off); off += SZ_QKV;  // partial N quarter 1
  ushort_t* np2 = (ushort_t*)(ws + off); off += SZ_QKV;  // partial N quarter 2
  ushort_t* np3 = (ushort_t*)(ws + off); off += SZ_QKV;  // partial N quarter 3
  float*    mlb = (float*)(ws + off); off += SZ_ML;      // (m,l)[4][BH][L]
  ushort_t* np0 = xbf;                                   // partial N quarter 0
  (void)ws_size; (void)n_in; (void)in_sizes; (void)out_size;

  cvt_f32_bf16<<<(B_ * L_ * C_ / 8 + 255) / 256, 256, 0, stream>>>(x, xbf, B_ * L_ * C_ / 8);
  cvt_f32_bf16<<<(3 * C_ * C_ / 8 + 255) / 256, 256, 0, stream>>>(wqkv, wqb, 3 * C_ * C_ / 8);
  cvt_f32_bf16<<<(C_ * C_ / 8 + 255) / 256, 256, 0, stream>>>(wproj, wpb, C_ * C_ / 8);
  pack_masks<<<dim3(L_, B_), 256, 0, stream>>>(adj, dist, a1p, d2p, d3p);
  hop2<<<B_ * L_ / 64, 64, 0, stream>>>(a1p, a2p);
  // qkv = x @ wqkv^T  (M=8192, N=2304, K=768), nwg=1152 (%8==0)
  // eye-head (sec2,h==0) output written directly into ob by the epilogue
  gemm_bt<0><<<dim3(3 * C_ / 128, B_ * L_ / 128), 256, 0, stream>>>(
      xbf, wqb, 3 * C_, C_, qb, kb, vTb, ob, nullptr);
  // attention split-K=4: 8-wave blocks, 256 q-rows, KVBLK=64 (4 chunks)
  attn_kernel<<<dim3(BH_, L_ / 256, 4), 512, 0, stream>>>(
      qb, kb, vTb, np0, np1, np2, np3, mlb, a1p, a2p, d2p, d3p);
  combine<<<dim3(BH_, L_ / 16), 256, 0, stream>>>(np0, np1, np2, np3, mlb, ob);
  // out = O @ wproj^T  (M=8192, N=768, K=768), nwg=384 (%8==0)
  gemm_bt<1><<<dim3(C_ / 128, B_ * L_ / 128), 256, 0, stream>>>(
      ob, wpb, C_, C_, nullptr, nullptr, nullptr, nullptr, out);
}

// Round 20
// 169.877 us; speedup vs baseline: 1.1867x; 1.0224x over previous
//
#include <hip/hip_runtime.h>

typedef unsigned short ushort_t;
typedef unsigned int uint_t;
typedef unsigned long long u64;
typedef __attribute__((ext_vector_type(8))) short bf16x8;
typedef __attribute__((ext_vector_type(4))) float f32x4;
typedef __attribute__((ext_vector_type(16))) float f32x16;
typedef __attribute__((ext_vector_type(4))) uint_t u32x4;

#define B_ 8
#define L_ 1024
#define C_ 768
#define H_ 6
#define D_ 128
#define BH_ 48
#define NEGINF (-1e9f)
#define THR_ 8.0f

#define AS1 __attribute__((address_space(1)))
#define AS3 __attribute__((address_space(3)))

// round-to-nearest-even f32 -> bf16
__device__ __forceinline__ ushort_t f2bf(float f) {
  uint_t u = __builtin_bit_cast(uint_t, f);
  u += 0x7fffu + ((u >> 16) & 1u);
  return (ushort_t)(u >> 16);
}
__device__ __forceinline__ float bf2f(ushort_t s) {
  uint_t u = ((uint_t)s) << 16;
  return __builtin_bit_cast(float, u);
}

// ------------------------------------------ fused converts (x, wqkv, wproj)
// block ranges: [0,3072) -> x (786432 u128s? no: 786432 threads), exact fits:
// x: 6291456/8 = 786432 = 3072*256; wqkv: 1769472/8 = 221184 = 864*256;
// wproj: 589824/8 = 73728 = 288*256.
__global__ __launch_bounds__(256)
void cvt_all(const float* __restrict__ x, const float* __restrict__ wqkv,
             const float* __restrict__ wproj,
             ushort_t* __restrict__ xbf, ushort_t* __restrict__ wqb,
             ushort_t* __restrict__ wpb) {
  int bid = blockIdx.x;
  const float* in;
  ushort_t* out;
  int i;
  if (bid < 3072)      { in = x;     out = xbf; i = bid * 256 + threadIdx.x; }
  else if (bid < 3936) { in = wqkv;  out = wqb; i = (bid - 3072) * 256 + threadIdx.x; }
  else                 { in = wproj; out = wpb; i = (bid - 3936) * 256 + threadIdx.x; }
  const float4* p = (const float4*)in + (size_t)i * 2;
  float4 a = p[0], b = p[1];
  uint4 r;
  r.x = (uint_t)f2bf(a.x) | ((uint_t)f2bf(a.y) << 16);
  r.y = (uint_t)f2bf(a.z) | ((uint_t)f2bf(a.w) << 16);
  r.z = (uint_t)f2bf(b.x) | ((uint_t)f2bf(b.y) << 16);
  r.w = (uint_t)f2bf(b.z) | ((uint_t)f2bf(b.w) << 16);
  ((uint4*)out)[i] = r;
}

// ------------------------------------------------- bit-pack a1 / d<=2 / d<=3
__global__ __launch_bounds__(256)
void pack_masks(const int* __restrict__ adj, const int* __restrict__ dist,
                u64* __restrict__ a1p, u64* __restrict__ d2p, u64* __restrict__ d3p) {
  int l = blockIdx.x, b = blockIdx.y, t = threadIdx.x;
  size_t base = ((size_t)b * L_ + l) * L_;
  size_t rb = ((size_t)b * L_ + l) * 16;
  #pragma unroll
  for (int it = 0; it < 4; ++it) {
    int c = it * 256 + t;
    int av = adj[base + c];
    int dv = dist[base + c];
    u64 m1 = __ballot((av > 0) || (c == l));
    u64 m2 = __ballot(dv <= 2);
    u64 m3 = __ballot(dv <= 3);
    if ((t & 63) == 0) {
      int w = it * 4 + (t >> 6);
      a1p[rb + w] = m1; d2p[rb + w] = m2; d3p[rb + w] = m3;
    }
  }
}

// ------------------------------------------------- 2-hop closure (bit OR)
__global__ __launch_bounds__(64)
void hop2(const u64* __restrict__ a1p, u64* __restrict__ a2p) {
  int tid = blockIdx.x * 64 + threadIdx.x;   // 0..8191 = (b,l)
  int b = tid >> 10;
  size_t rb = (size_t)tid * 16;
  u64 row[16], acc[16];
  #pragma unroll
  for (int j = 0; j < 16; ++j) { row[j] = a1p[rb + j]; acc[j] = 0ULL; }
  bool done = false;
  #pragma unroll
  for (int mw = 0; mw < 16; ++mw) {
    if (done) continue;
    u64 bits = row[mw];
    while (bits) {
      int tz = __builtin_ctzll(bits); bits &= bits - 1;
      const u64* src = a1p + (((size_t)b << 10) + (mw << 6) + tz) * 16;
      u64 band = ~0ULL;
      #pragma unroll
      for (int j = 0; j < 16; ++j) { acc[j] |= src[j]; band &= acc[j]; }
      if (band == ~0ULL) { done = true; break; }
    }
  }
  #pragma unroll
  for (int j = 0; j < 16; ++j) a2p[rb + j] = acc[j];
}

// ------------------------------------------------- bf16 GEMM  C = A @ B^T
// 128x128 tile, BK=64, T2 both-sides XOR swizzle, bijective XCD swizzle.
// EPI==0 epilogue is BLOCK-UNIFORM in sec (n-tiles 128-wide, 768%128==0):
//   sec0 -> q (scaled), sec1 -> k, sec2 h==0 -> eye-head output DIRECTLY
//   into ob (out = v for the eye mask; h*D==0), sec2 h!=0 -> vT via LDS
//   transpose.
template<int EPI>
__global__ __launch_bounds__(256)
void gemm_bt(const ushort_t* __restrict__ A, const ushort_t* __restrict__ Bm,
             int N, int K,
             ushort_t* __restrict__ qo, ushort_t* __restrict__ ko,
             ushort_t* __restrict__ vTo, ushort_t* __restrict__ obf,
             float* __restrict__ fo) {
  __shared__ __align__(16) ushort_t As[128 * 64];   // 16 KB
  __shared__ __align__(16) ushort_t Bs[128 * 64];   // 16 KB
  int t = threadIdx.x;
  int lane = t & 63, lo = lane & 15, hi = lane >> 4;
  int wv = t >> 6, wm = wv >> 1, wn = wv & 1;

  int gx = gridDim.x;
  int nwg = gx * gridDim.y;
  int orig = blockIdx.y * gx + blockIdx.x;
  int cpx = nwg >> 3;
  int wg = (orig & 7) * cpx + (orig >> 3);
  int n0 = (wg % gx) * 128;
  int m0 = (wg / gx) * 128;

  f32x4 acc[4][4];
  #pragma unroll
  for (int mi = 0; mi < 4; ++mi)
    #pragma unroll
    for (int ni = 0; ni < 4; ++ni) acc[mi][ni] = (f32x4){0.f, 0.f, 0.f, 0.f};

  for (int kt = 0; kt < K; kt += 64) {
    #pragma unroll
    for (int i = 0; i < 4; ++i) {
      int u = i * 256 + t;                 // 0..1023
      int row = u >> 3, c16 = u & 7;
      int sc = c16 ^ (row & 7);
      __builtin_amdgcn_global_load_lds(
          (const AS1 void*)(A + ((size_t)(m0 + row) * K + kt + sc * 8)),
          (AS3 void*)&As[(size_t)u * 8], 16, 0, 0);
      __builtin_amdgcn_global_load_lds(
          (const AS1 void*)(Bm + ((size_t)(n0 + row) * K + kt + sc * 8)),
          (AS3 void*)&Bs[(size_t)u * 8], 16, 0, 0);
    }
    __syncthreads();
    #pragma unroll
    for (int kks = 0; kks < 2; ++kks) {
      bf16x8 af[4], bfr[4];
      #pragma unroll
      for (int mi = 0; mi < 4; ++mi) {
        int r = wm * 64 + mi * 16 + lo;
        af[mi] = *(const bf16x8*)&As[r * 64 + (((kks * 4 + hi) ^ (r & 7)) * 8)];
      }
      #pragma unroll
      for (int ni = 0; ni < 4; ++ni) {
        int r = wn * 64 + ni * 16 + lo;
        bfr[ni] = *(const bf16x8*)&Bs[r * 64 + (((kks * 4 + hi) ^ (r & 7)) * 8)];
      }
      #pragma unroll
      for (int mi = 0; mi < 4; ++mi)
        #pragma unroll
        for (int ni = 0; ni < 4; ++ni)
          acc[mi][ni] = __builtin_amdgcn_mfma_f32_16x16x32_bf16(af[mi], bfr[ni], acc[mi][ni], 0, 0, 0);
    }
    __syncthreads();
  }

  // epilogue. D layout: col = lane&15, row = (lane>>4)*4 + j  [m89-verified]
  if (EPI == 1) {
    #pragma unroll
    for (int mi = 0; mi < 4; ++mi) {
      int rbase = m0 + wm * 64 + mi * 16 + hi * 4;
      #pragma unroll
      for (int ni = 0; ni < 4; ++ni) {
        int c = n0 + wn * 64 + ni * 16 + lo;
        f32x4 v = acc[mi][ni];
        #pragma unroll
        for (int j = 0; j < 4; ++j)
          fo[(size_t)(rbase + j) * N + c] = v[j];
      }
    }
    return;
  }
  // EPI == 0: block-uniform section
  int sec = n0 / 768;
  if (sec < 2) {
    #pragma unroll
    for (int mi = 0; mi < 4; ++mi) {
      int rbase = m0 + wm * 64 + mi * 16 + hi * 4;
      #pragma unroll
      for (int ni = 0; ni < 4; ++ni) {
        int cc = n0 - sec * 768 + wn * 64 + ni * 16 + lo;
        int hh = cc >> 7, dd = cc & 127;
        f32x4 v = acc[mi][ni];
        #pragma unroll
        for (int j = 0; j < 4; ++j) {
          int r = rbase + j;
          int b = r >> 10, l = r & 1023;
          size_t bh = (size_t)(b * H_ + hh);
          if (sec == 0) qo[(bh * L_ + l) * D_ + dd] = f2bf(v[j] * 0.08838834764831845f);
          else          ko[(bh * L_ + l) * D_ + dd] = f2bf(v[j]);
        }
      }
    }
    return;
  }
  // sec == 2: V third. h is block-uniform.
  int hh = (n0 - 1536) >> 7;
  int b = m0 >> 10, l0 = m0 & 1023;
  size_t bh = (size_t)(b * H_ + hh);
  if (hh == 0) {
    // eye head: softmax over diagonal element == v -> write final output
    // directly (h*D_ == 0 column offset in ob)
    #pragma unroll
    for (int mi = 0; mi < 4; ++mi) {
      int lb = wm * 64 + mi * 16 + hi * 4;
      #pragma unroll
      for (int ni = 0; ni < 4; ++ni) {
        int dd = wn * 64 + ni * 16 + lo;
        f32x4 v = acc[mi][ni];
        #pragma unroll
        for (int j = 0; j < 4; ++j)
          obf[((size_t)b * L_ + l0 + lb + j) * C_ + dd] = f2bf(v[j]);
      }
    }
    return;
  }
  // h != 0: only vT needed. LDS transpose, XOR (dd&7)<<4 both sides.
  #pragma unroll
  for (int mi = 0; mi < 4; ++mi) {
    int lb = wm * 64 + mi * 16 + hi * 4;
    #pragma unroll
    for (int ni = 0; ni < 4; ++ni) {
      int dd = wn * 64 + ni * 16 + lo;
      ushort_t* base = (dd < 64) ? As : Bs;
      f32x4 v = acc[mi][ni];
      #pragma unroll
      for (int j = 0; j < 4; ++j) {
        int byte = (((dd & 63) * 256 + (lb + j) * 2)) ^ ((dd & 7) << 4);
        *(ushort_t*)((char*)base + byte) = f2bf(v[j]);
      }
    }
  }
  __syncthreads();
  #pragma unroll
  for (int i = 0; i < 8; ++i) {
    int u = i * 256 + t;            // 2048 chunks: dd 0..127 x 16 16B-chunks
    int ddl = u >> 4, c16 = u & 15;
    const ushort_t* base = (ddl < 64) ? As : Bs;
    int byte = (((ddl & 63) * 256 + c16 * 16)) ^ ((ddl & 7) << 4);
    bf16x8 val = *(const bf16x8*)((const char*)base + byte);
    *(bf16x8*)(vTo + (bh * D_ + ddl) * L_ + l0 + c16 * 8) = val;
  }
}

// ------------------------------------------------- flash attention, split-K=4
// 8 waves / block, 256 q-rows (32/wave); kv quarter per blockIdx.z.
// KVBLK=64: 4 chunks/block; two 32-k subtiles per chunk (R18-verified).
// Eye head (h==0) handled entirely by the qkv GEMM epilogue -> instant return.
__global__ __launch_bounds__(512)
void attn_kernel(const ushort_t* __restrict__ q, const ushort_t* __restrict__ k,
                 const ushort_t* __restrict__ vT,
                 ushort_t* __restrict__ np0, ushort_t* __restrict__ np1,
                 ushort_t* __restrict__ np2, ushort_t* __restrict__ np3,
                 float* __restrict__ ml,
                 const u64* __restrict__ a1p, const u64* __restrict__ a2p,
                 const u64* __restrict__ d2p, const u64* __restrict__ d3p) {
  __shared__ __align__(16) ushort_t Ks[2][64 * 128];   // [krow][d]  16 KB x2
  __shared__ __align__(16) ushort_t Vs[2][128 * 64];   // [d][kcol]  16 KB x2
  int t = threadIdx.x;
  int lane = t & 63, lo32 = lane & 31, hi2 = (lane >> 5) & 1, wv = t >> 6;
  int bh = blockIdx.x, qt = blockIdx.y, quar = blockIdx.z;
  int b = bh / H_, h = bh - b * H_;
  int qbase = qt * 256;
  int qw = qbase + wv * 32;
  int kvb = quar * 256;

  if (h == 0) return;   // eye head written directly by the qkv GEMM epilogue

  const ushort_t* qp = q + (size_t)bh * L_ * D_;
  const ushort_t* kp = k + (size_t)bh * L_ * D_ + (size_t)kvb * D_;
  const ushort_t* vp = vT + (size_t)bh * D_ * L_ + kvb;

  bf16x8 qf[8];
  #pragma unroll
  for (int dt = 0; dt < 8; ++dt)
    qf[dt] = *(const bf16x8*)(qp + (size_t)(qw + lo32) * D_ + dt * 16 + hi2 * 8);

  const u64* mp = (h == 1) ? a1p : (h == 2) ? a2p : (h == 3) ? d2p : d3p;
  bool full = (h == 5);
  const u64* mrow = mp + ((size_t)b * L_ + qw + lo32) * 16 + quar * 4;

  float m_run = NEGINF, l_run = 0.f;
  f32x16 acc[4];
  #pragma unroll
  for (int dt = 0; dt < 4; ++dt)
    #pragma unroll
    for (int r = 0; r < 16; ++r) acc[dt][r] = 0.f;

  // stage one 64-col K/V chunk: 4 global_load_lds per thread (512 threads)
  auto stage = [&](int buf, int ch) {
    int kc0 = ch * 64;
    #pragma unroll
    for (int i = 0; i < 2; ++i) {
      int u = i * 512 + t;                 // K: 64 rows x 16 slots (1024 chunks)
      int row = u >> 4, c16 = u & 15;
      int sc = c16 ^ (row & 15);
      __builtin_amdgcn_global_load_lds(
          (const AS1 void*)(kp + (size_t)(kc0 + row) * D_ + sc * 8),
          (AS3 void*)&Ks[buf][(size_t)u * 8], 16, 0, 0);
    }
    #pragma unroll
    for (int i = 0; i < 2; ++i) {
      int u = i * 512 + t;                 // V: 128 rows x 8 slots (1024 chunks)
      int row = u >> 3, c16 = u & 7;
      int sc = c16 ^ (row & 7);
      __builtin_amdgcn_global_load_lds(
          (const AS1 void*)(vp + (size_t)row * L_ + kc0 + sc * 8),
          (AS3 void*)&Vs[buf][(size_t)u * 8], 16, 0, 0);
    }
  };

  stage(0, 0);
  u64 mw_cur = full ? 0ULL : mrow[0];
  u64 mw_nxt = 0ULL;
  __syncthreads();

  for (int ch = 0; ch < 4; ++ch) {
    int cur = ch & 1;
    if (ch < 3) { stage(cur ^ 1, ch + 1); if (!full) mw_nxt = mrow[ch + 1]; }

    const ushort_t* ks = &Ks[cur][0];
    const ushort_t* vs = &Vs[cur][0];

    #pragma unroll
    for (int s = 0; s < 2; ++s) {                   // two 32-k subtiles
      // S^T subtile: sacc[r] = S[q=lo32][kvb + 64ch + 32s + crow(r,hi2)]
      f32x16 sacc;
      #pragma unroll
      for (int r = 0; r < 16; ++r) sacc[r] = 0.f;
      __builtin_amdgcn_s_setprio(1);
      #pragma unroll
      for (int dt = 0; dt < 8; ++dt) {
        int krow = s * 32 + lo32;
        int c16 = (dt * 2 + hi2) ^ (krow & 15);
        bf16x8 kf = *(const bf16x8*)&ks[krow * 128 + c16 * 8];
        sacc = __builtin_amdgcn_mfma_f32_32x32x16_bf16(kf, qf[dt], sacc, 0, 0, 0);
      }
      __builtin_amdgcn_s_setprio(0);

      uint_t mbits = full ? 0xffffffffu : (uint_t)(mw_cur >> (32 * s));
      float sv[16];
      #pragma unroll
      for (int r = 0; r < 16; ++r) {
        int shift = (r & 3) + 8 * (r >> 2) + hi2 * 4;
        sv[r] = ((mbits >> shift) & 1u) ? sacc[r] : NEGINF;
      }

      // in-lane max tree + 1 cross-lane
      float a8[8];
      #pragma unroll
      for (int j = 0; j < 8; ++j) a8[j] = fmaxf(sv[2 * j], sv[2 * j + 1]);
      #pragma unroll
      for (int j = 0; j < 4; ++j) a8[j] = fmaxf(a8[j], a8[j + 4]);
      float pmax = fmaxf(fmaxf(a8[0], a8[1]), fmaxf(a8[2], a8[3]));
      pmax = fmaxf(pmax, __shfl_xor(pmax, 32));

      // defer-max (T13)
      if (__any(pmax > m_run + THR_)) {
        float mn = fmaxf(m_run, pmax);
        float corr = __expf(m_run - mn);
        l_run *= corr;
        m_run = mn;
        float cT[16];
        #pragma unroll
        for (int r = 0; r < 16; ++r)
          cT[r] = __shfl(corr, (r & 3) + 8 * (r >> 2) + hi2 * 4);
        #pragma unroll
        for (int dt = 0; dt < 4; ++dt)
          #pragma unroll
          for (int r = 0; r < 16; ++r) acc[dt][r] *= cT[r];
      }

      // P = exp(S - m_run); row-sum
      float p[16];
      #pragma unroll
      for (int r = 0; r < 16; ++r) p[r] = __expf(sv[r] - m_run);
      float s8[8];
      #pragma unroll
      for (int j = 0; j < 8; ++j) s8[j] = p[2 * j] + p[2 * j + 1];
      #pragma unroll
      for (int j = 0; j < 4; ++j) s8[j] = s8[j] + s8[j + 4];
      float rs = (s8[0] + s8[1]) + (s8[2] + s8[3]);
      rs += __shfl_xor(rs, 32);
      l_run += rs;

      // pack P; half-swap to build PV A-frags (R6/R8-verified)
      uint_t ow[8];
      #pragma unroll
      for (int j = 0; j < 8; ++j)
        ow[j] = (uint_t)f2bf(p[2 * j]) | ((uint_t)f2bf(p[2 * j + 1]) << 16);
      uint_t pw[8];
      #pragma unroll
      for (int j = 0; j < 8; ++j) pw[j] = __shfl_xor(ow[j], 32);
      u32x4 pa0 = (u32x4){hi2 ? pw[2] : ow[0], hi2 ? pw[3] : ow[1],
                          hi2 ? ow[2] : pw[0], hi2 ? ow[3] : pw[1]};
      u32x4 pa1 = (u32x4){hi2 ? pw[6] : ow[4], hi2 ? pw[7] : ow[5],
                          hi2 ? ow[6] : pw[4], hi2 ? ow[7] : pw[5]};
      bf16x8 paf0 = __builtin_bit_cast(bf16x8, pa0);
      bf16x8 paf1 = __builtin_bit_cast(bf16x8, pa1);

      // PV: B-frags from swizzled Vs (R8-verified slot math)
      __builtin_amdgcn_s_setprio(1);
      #pragma unroll
      for (int dt = 0; dt < 4; ++dt) {
        int vd = dt * 32 + lo32;
        int c16a = (s * 4 + hi2) ^ (vd & 7);
        int c16b = (s * 4 + 2 + hi2) ^ (vd & 7);
        bf16x8 vfa = *(const bf16x8*)&vs[vd * 64 + c16a * 8];
        bf16x8 vfb = *(const bf16x8*)&vs[vd * 64 + c16b * 8];
        acc[dt] = __builtin_amdgcn_mfma_f32_32x32x16_bf16(paf0, vfa, acc[dt], 0, 0, 0);
        acc[dt] = __builtin_amdgcn_mfma_f32_32x32x16_bf16(paf1, vfb, acc[dt], 0, 0, 0);
      }
      __builtin_amdgcn_s_setprio(0);
    }
    mw_cur = mw_nxt;
    __syncthreads();
  }

  // epilogue: write partials. (m,l) per q-row (hi2==0 lanes); N unnormalized bf16.
  if (hi2 == 0) {
    size_t row = (size_t)bh * L_ + qw + lo32;
    float2 v2 = make_float2(m_run, l_run);
    *(float2*)(ml + ((size_t)quar * BH_ * L_ + row) * 2) = v2;
  }
  ushort_t* np = (quar == 0) ? np0 : (quar == 1) ? np1 : (quar == 2) ? np2 : np3;
  #pragma unroll
  for (int dt = 0; dt < 4; ++dt)
    #pragma unroll
    for (int r = 0; r < 16; ++r) {
      int qrow = qw + (r & 3) + 8 * (r >> 2) + hi2 * 4;
      np[((size_t)bh * L_ + qrow) * D_ + dt * 32 + lo32] = f2bf(acc[dt][r]);
    }
}

// ------------------------------------------------- split-K combine (4-way)
__global__ __launch_bounds__(256)
void combine(const ushort_t* __restrict__ np0, const ushort_t* __restrict__ np1,
             const ushort_t* __restrict__ np2, const ushort_t* __restrict__ np3,
             const float* __restrict__ ml, ushort_t* __restrict__ obf) {
  int bh = blockIdx.x;
  int b = bh / H_, h = bh - b * H_;
  if (h == 0) return;                       // eye head written by qkv GEMM
  int t = threadIdx.x;
  int qi = t >> 4, di = t & 15;             // 16 q-rows x 16 d-groups of 8
  int qq = blockIdx.y * 16 + qi;
  size_t row = (size_t)bh * L_ + qq;
  float2 mlv[4];
  #pragma unroll
  for (int s = 0; s < 4; ++s)
    mlv[s] = *(const float2*)(ml + ((size_t)s * BH_ * L_ + row) * 2);
  float M = fmaxf(fmaxf(mlv[0].x, mlv[1].x), fmaxf(mlv[2].x, mlv[3].x));
  float w[4], lsum = 0.f;
  #pragma unroll
  for (int s = 0; s < 4; ++s) { w[s] = __expf(mlv[s].x - M); lsum += w[s] * mlv[s].y; }
  float inv = 1.f / lsum;
  bf16x8 n0 = *(const bf16x8*)(np0 + row * D_ + di * 8);
  bf16x8 n1 = *(const bf16x8*)(np1 + row * D_ + di * 8);
  bf16x8 n2 = *(const bf16x8*)(np2 + row * D_ + di * 8);
  bf16x8 n3 = *(const bf16x8*)(np3 + row * D_ + di * 8);
  ushort_t o[8];
  #pragma unroll
  for (int j = 0; j < 8; ++j)
    o[j] = f2bf((w[0] * bf2f((ushort_t)n0[j]) + w[1] * bf2f((ushort_t)n1[j]) +
                 w[2] * bf2f((ushort_t)n2[j]) + w[3] * bf2f((ushort_t)n3[j])) * inv);
  *(bf16x8*)(obf + ((size_t)b * L_ + qq) * C_ + h * D_ + di * 8) = *(bf16x8*)o;
}

// ---------------------------------------------------------------- launcher
extern "C" void kernel_launch(void* const* d_in, const int* in_sizes, int n_in,
                              void* d_out, int out_size, void* d_ws, size_t ws_size,
                              hipStream_t stream) {
  const float* x     = (const float*)d_in[0];
  const int*   adj   = (const int*)d_in[1];
  const int*   dist  = (const int*)d_in[2];
  const float* wqkv  = (const float*)d_in[3];
  const float* wproj = (const float*)d_in[4];
  float* out = (float*)d_out;
  char* ws = (char*)d_ws;

  const size_t SZ_X   = (size_t)B_ * L_ * C_ * 2;        // 12.6 MB (== SZ_QKV)
  const size_t SZ_WQ  = (size_t)3 * C_ * C_ * 2;
  const size_t SZ_WP  = (size_t)C_ * C_ * 2;
  const size_t SZ_QKV = (size_t)BH_ * L_ * D_ * 2;       // 12.6 MB
  const size_t SZ_MSK = (size_t)B_ * L_ * 16 * 8;        // 1 MB
  const size_t SZ_ML  = (size_t)4 * BH_ * L_ * 2 * 4;    // 1.6 MB
  size_t off = 0;
  ushort_t* xbf  = (ushort_t*)(ws + off); off += SZ_X;   // reused as np0 post-GEMM
  ushort_t* wqb  = (ushort_t*)(ws + off); off += SZ_WQ;
  ushort_t* wpb  = (ushort_t*)(ws + off); off += SZ_WP;
  ushort_t* qb   = (ushort_t*)(ws + off); off += SZ_QKV;
  ushort_t* kb   = (ushort_t*)(ws + off); off += SZ_QKV;
  ushort_t* vTb  = (ushort_t*)(ws + off); off += SZ_QKV;
  ushort_t* ob   = (ushort_t*)(ws + off); off += SZ_X;
  u64* a1p = (u64*)(ws + off); off += SZ_MSK;
  u64* a2p = (u64*)(ws + off); off += SZ_MSK;
  u64* d2p = (u64*)(ws + off); off += SZ_MSK;
  u64* d3p = (u64*)(ws + off); off += SZ_MSK;
  ushort_t* np1 = (ushort_t*)(ws + off); off += SZ_QKV;  // partial N quarter 1
  ushort_t* np2 = (ushort_t*)(ws + off); off += SZ_QKV;  // partial N quarter 2
  ushort_t* np3 = (ushort_t*)(ws + off); off += SZ_QKV;  // partial N quarter 3
  float*    mlb = (float*)(ws + off); off += SZ_ML;      // (m,l)[4][BH][L]
  ushort_t* np0 = xbf;                                   // partial N quarter 0
  (void)ws_size; (void)n_in; (void)in_sizes; (void)out_size;

  // fused converts: 3072 (x) + 864 (wqkv) + 288 (wproj) blocks
  cvt_all<<<3072 + 864 + 288, 256, 0, stream>>>(x, wqkv, wproj, xbf, wqb, wpb);
  pack_masks<<<dim3(L_, B_), 256, 0, stream>>>(adj, dist, a1p, d2p, d3p);
  hop2<<<B_ * L_ / 64, 64, 0, stream>>>(a1p, a2p);
  // qkv = x @ wqkv^T  (M=8192, N=2304, K=768), nwg=1152 (%8==0)
  // eye-head (sec2,h==0) output written directly into ob by the epilogue
  gemm_bt<0><<<dim3(3 * C_ / 128, B_ * L_ / 128), 256, 0, stream>>>(
      xbf, wqb, 3 * C_, C_, qb, kb, vTb, ob, nullptr);
  // attention split-K=4: 8-wave blocks, 256 q-rows, KVBLK=64 (4 chunks)
  attn_kernel<<<dim3(BH_, L_ / 256, 4), 512, 0, stream>>>(
      qb, kb, vTb, np0, np1, np2, np3, mlb, a1p, a2p, d2p, d3p);
  combine<<<dim3(BH_, L_ / 16), 256, 0, stream>>>(np0, np1, np2, np3, mlb, ob);
  // out = O @ wproj^T  (M=8192, N=768, K=768), nwg=384 (%8==0)
  gemm_bt<1><<<dim3(C_ / 128, B_ * L_ / 128), 256, 0, stream>>>(
      ob, wpb, C_, C_, nullptr, nullptr, nullptr, nullptr, out);
}